// Round 7
// baseline (394.185 us; speedup 1.0000x reference)
//
#include <hip/hip_runtime.h>
#include <hip/hip_fp16.h>
#include <math.h>

#define EPSF 1e-5f

typedef __attribute__((ext_vector_type(4))) float  floatx4;
typedef __attribute__((ext_vector_type(4))) short  short4v;
typedef __attribute__((ext_vector_type(8))) short  short8v;

__device__ __forceinline__ unsigned short cvt_bf16(float f){
  unsigned u = __float_as_uint(f);
  unsigned r = (u + 0x7FFFu + ((u >> 16) & 1u)) >> 16;
  return (unsigned short)r;
}
__device__ __forceinline__ float bf2f(unsigned short h){
  return __uint_as_float(((unsigned)h) << 16);
}
__device__ __forceinline__ short8v ld_frag(const unsigned short* p){
  short4v lo = *(const short4v*)p;
  short4v hi = *(const short4v*)(p + 4);
  return __builtin_shufflevector(lo, hi, 0,1,2,3,4,5,6,7);
}
__device__ __forceinline__ float lrelu(float x){ return x >= 0.f ? x : 0.2f*x; }

// ---- merged prep. Weights fragment-packed: [co16grp][tap][ccgrp][lane64][8]
// b-frag lane mapping (16x16x32): co_local = lane&15, k = (lane>>4)*8 + j.
__global__ __launch_bounds__(256) void prep_k(const float* __restrict__ w1, const float* __restrict__ w2,
                                              const float* __restrict__ w3, const float* __restrict__ w4,
                                              unsigned short* __restrict__ wb1, unsigned short* __restrict__ wb2,
                                              unsigned short* __restrict__ wb3, unsigned short* __restrict__ wb4,
                                              float* __restrict__ SQ){
  int b = blockIdx.x, t = threadIdx.x;
  if (b < 32){                       // conv1: 4 grp x 4 ks x 512; k=(kh*6+kw)*4+ci over K=128
    int idx = b*256 + t;             // 8192 shorts
    int j = idx&7, lane = (idx>>3)&63, ks = (idx>>9)&3, grp = idx>>11;
    int co = grp*16 + (lane&15);
    int k = ks*32 + ((lane>>4)<<3) + j;
    int tap6 = k>>2, ci = k&3;
    int kh = tap6/6, kw = tap6 - kh*6;
    float v = 0.f;
    if (ci < 3 && kh < 5 && kw < 5) v = w1[(co*3 + ci)*25 + kh*5 + kw];
    wb1[idx] = cvt_bf16(v);
  } else if (b < 832){               // conv2: 8 grp x 25 tap x 2 ccg x 512 = 204800
    int idx = (b-32)*256 + t;
    int grp = idx/25600, rem = idx - grp*25600;
    int tap = rem/1024, rem2 = rem - tap*1024;
    int ccg = rem2>>9, lane = (rem2>>3)&63, j = rem2&7;
    int co = grp*16 + (lane&15);
    int ci = ccg*32 + ((lane>>4)<<3) + j;
    wb2[idx] = cvt_bf16(w2[(co*64 + ci)*25 + tap]);
  } else if (b < 4032){              // conv3: 16 grp x 25 tap x 4 ccg x 512 = 819200
    int idx = (b-832)*256 + t;
    int grp = idx/51200, rem = idx - grp*51200;
    int tap = rem/2048, rem2 = rem - tap*2048;
    int ccg = rem2>>9, lane = (rem2>>3)&63, j = rem2&7;
    int co = grp*16 + (lane&15);
    int ci = ccg*32 + ((lane>>4)<<3) + j;
    wb3[idx] = cvt_bf16(w3[(co*128 + ci)*25 + tap]);
  } else if (b < 6336){              // conv4: 16 grp x 9 tap x 8 ccg x 512 = 589824
    int idx = (b-4032)*256 + t;
    int grp = idx/36864, rem = idx - grp*36864;
    int tap = rem/4096, rem2 = rem - tap*4096;
    int ccg = rem2>>9, lane = (rem2>>3)&63, j = rem2&7;
    int co = grp*16 + (lane&15);
    int ci = ccg*32 + ((lane>>4)<<3) + j;
    wb4[idx] = cvt_bf16(w4[(co*256 + ci)*9 + tap]);
  } else {                           // zero S1/Q1/S2/Q2 (98304 floats)
    int idx = (b-6336)*256 + t;
    SQ[idx] = 0.f;
  }
}

// ---- packT_k: T (4096x3200 fp32) -> bf16 MFMA b-fragment layout.
// Tp: [ngrp(200)][ktile(128)][lane(64)][8]; aliases dead f1raw (launched after conv2).
__global__ __launch_bounds__(256) void packT_k(const float* __restrict__ T,
                                               unsigned short* __restrict__ Tp){
  const int b = blockIdx.x, t = threadIdx.x;
  __shared__ float tile[32][133];
  const int nb = b % 25, kt = b / 25;
  const int n0 = nb*128, k0 = kt*32;
  #pragma unroll
  for (int m=0;m<4;m++){
    int idx = m*256 + t;
    int row = idx>>5, c4 = (idx&31)<<2;
    const float4 v = *(const float4*)&T[(k0+row)*3200 + n0 + c4];
    tile[row][c4]   = v.x; tile[row][c4+1] = v.y;
    tile[row][c4+2] = v.z; tile[row][c4+3] = v.w;
  }
  __syncthreads();
  #pragma unroll
  for (int m=0;m<2;m++){
    int c = m*256 + t;
    int ngl = c>>6, lane = c&63, q = lane>>4, r = lane&15;
    unsigned short h[8];
    #pragma unroll
    for (int j=0;j<8;j++) h[j] = cvt_bf16(tile[q*8+j][ngl*16 + r]);
    *(uint4*)&Tp[(((nb*8 + ngl)*128 + kt)*64 + lane)*8] = *(const uint4*)h;
  }
}

// ---- packW_k: fcw (1000x4160 fp32) -> bf16 b-fragment layout. Aliases Mp (after reduceM).
__global__ __launch_bounds__(256) void packW_k(const float* __restrict__ W,
                                               unsigned short* __restrict__ Wp){
  int idx = blockIdx.x*256 + threadIdx.x;   // 532480 chunks of 8
  int lane = idx & 63, rem = idx >> 6;
  int kt = rem % 130, ng = rem / 130;
  int q = lane>>4, r = lane&15;
  int orow = ng*16 + r, k = kt*32 + (q<<3);
  unsigned short h[8] = {0,0,0,0,0,0,0,0};
  if (orow < 1000){
    float4 v0 = *(const float4*)&W[orow*4160 + k];
    float4 v1 = *(const float4*)&W[orow*4160 + k + 4];
    h[0]=cvt_bf16(v0.x); h[1]=cvt_bf16(v0.y); h[2]=cvt_bf16(v0.z); h[3]=cvt_bf16(v0.w);
    h[4]=cvt_bf16(v1.x); h[5]=cvt_bf16(v1.y); h[6]=cvt_bf16(v1.z); h[7]=cvt_bf16(v1.w);
  }
  *(uint4*)&Wp[idx*8] = *(const uint4*)h;
}

// ---- conv1: half-image blocks (grid 512). Raw f1 + S1/Q1 atomics.
// img has 36 rows: row 35 is an always-zero guard row (kh=5 pad taps land there).
__global__ __launch_bounds__(256) void conv1_k(const float* __restrict__ x, const unsigned short* __restrict__ wb1P,
                                               float* __restrict__ S1, float* __restrict__ Q1,
                                               unsigned short* __restrict__ f1raw){
  const int t = threadIdx.x, n = blockIdx.x>>1, half = blockIdx.x&1;
  const int w = t>>6, lane = t&63, q = lane>>4, l16 = lane&15;
  __shared__ __align__(16) unsigned short img[36*68*4];   // [tih][iw+2][ci] 19.6 KB
  short8v bf[4][4];
  #pragma unroll
  for (int nt=0;nt<4;nt++)
    #pragma unroll
    for (int ks=0;ks<4;ks++)
      bf[nt][ks] = *(const short8v*)&wb1P[((nt*4+ks)*64 + lane)*8];
  for (int i=t; i<4896; i+=256) ((unsigned*)img)[i] = 0u;
  __syncthreads();
  for (int idx=t; idx<1680; idx+=256){
    int ci = idx/560, rem = idx - ci*560;
    int tih = rem>>4, iw4 = (rem&15)<<2;
    int ih = half*32 - 2 + tih;
    if ((unsigned)ih < 64u){
      float4 v = *(const float4*)&x[((n*3+ci)<<12) + (ih<<6) + iw4];
      int base = (tih*68 + iw4 + 2)*4 + ci;
      img[base]    = cvt_bf16(v.x);
      img[base+4]  = cvt_bf16(v.y);
      img[base+8]  = cvt_bf16(v.z);
      img[base+12] = cvt_bf16(v.w);
    }
  }
  __syncthreads();
  floatx4 acc[8][4];
  #pragma unroll
  for (int mi=0;mi<8;mi++)
    #pragma unroll
    for (int nt=0;nt<4;nt++) acc[mi][nt] = (floatx4){0.f,0.f,0.f,0.f};
  #pragma unroll
  for (int mi=0; mi<8; mi++){
    int r = w*8 + mi;                 // mtile 0..31 within half
    int ohl = r>>1, ow = ((r&1)<<4) + l16;
    #pragma unroll
    for (int ks=0; ks<4; ks++){
      int t0 = ks*8 + 2*q;
      int kh = t0/6, kw = t0 - kh*6;
      short8v a = ld_frag(&img[((ohl*2+kh)*68 + ow*2 + kw)*4]);
      #pragma unroll
      for (int nt=0; nt<4; nt++)
        acc[mi][nt] = __builtin_amdgcn_mfma_f32_16x16x32_bf16(a, bf[nt][ks], acc[mi][nt], 0,0,0);
    }
  }
  float sreg[4] = {0,0,0,0}, qreg[4] = {0,0,0,0};
  #pragma unroll
  for (int mi=0;mi<8;mi++){
    int r = w*8 + mi;
    #pragma unroll
    for (int nt=0;nt<4;nt++)
      #pragma unroll
      for (int e=0;e<4;e++){
        float v = acc[mi][nt][e];
        sreg[nt] += v; qreg[nt] += v*v;
        int px = half*512 + (r<<4) + (q<<2) + e;
        f1raw[(((n<<10)+px)<<6) + (nt<<4) + l16] = cvt_bf16(v);
      }
  }
  #pragma unroll
  for (int nt=0;nt<4;nt++){
    float s = sreg[nt], qq = qreg[nt];
    s  += __shfl_xor(s,16,64);  s  += __shfl_xor(s,32,64);
    qq += __shfl_xor(qq,16,64); qq += __shfl_xor(qq,32,64);
    if (q==0){
      atomicAdd(&S1[(n<<6) + (nt<<4) + l16], s);
      atomicAdd(&Q1[(n<<6) + (nt<<4) + l16], qq);
    }
  }
}

// ---- conv2: Mb=128 x Nb=128, grid 512 x 512thr. 4-deep B ring.
// LDS slot swizzle: cell's four 16B slots permuted by s^=((cell>>3)&1) on BOTH
// write (staging) and read (a-frag) -> quarter-wave a-reads cover all 32 banks.
__global__ __launch_bounds__(512) void conv2_k(const unsigned short* __restrict__ fin,
                                               const unsigned short* __restrict__ wbP,
                                               const float* __restrict__ S1, const float* __restrict__ Q1,
                                               const float* __restrict__ g1, const float* __restrict__ be1,
                                               float* __restrict__ S2, float* __restrict__ Q2,
                                               unsigned short* __restrict__ fout){
  const int t = threadIdx.x;
  const int n = blockIdx.x >> 1, half = blockIdx.x & 1;
  const int w = t>>6, lane = t&63, q = lane>>4, l16 = lane&15;
  const int rw = w&1, cw = w>>1;           // rw 0..1, cw 0..3
  __shared__ __align__(16) unsigned short tile[684*40];   // 19x36 cells, 54.7 KB
  __shared__ float gmA[64], btA[64];
  if (t < 64){
    float S = S1[(n<<6)+t], Q = Q1[(n<<6)+t];
    float mu = S*(1.f/1024.f), var = fmaxf(Q*(1.f/1024.f) - mu*mu, 0.f);
    float r = rsqrtf(var+EPSF)*g1[t];
    gmA[t] = r; btA[t] = be1[t] - mu*r;
  }
  __syncthreads();
  floatx4 acc[4][2];
  #pragma unroll
  for (int mt=0;mt<4;mt++)
    #pragma unroll
    for (int nt=0;nt<2;nt++) acc[mt][nt] = (floatx4){0.f,0.f,0.f,0.f};
  int cellb[4];
  #pragma unroll
  for (int mt=0;mt<4;mt++){
    int r = rw*64 + mt*16 + l16;
    int ohl = r>>4, ow = r&15;
    cellb[mt] = (2*ohl)*36 + 2*ow;
  }
  for (int ccg = 0; ccg < 2; ccg++){
    const int cc = ccg<<5;
    if (ccg) __syncthreads();
    #pragma unroll
    for (int it=0; it<6; it++){
      int idx = it*512 + t;
      if (idx < 2736){
        int cell = idx>>2, s = idx&3;
        int s2 = s ^ ((cell>>3)&1);            // slot swizzle
        int ci0 = s<<3;
        int tih = cell/36, tiw = cell - tih*36;
        int ih = half*16 + tih - 2, iw = tiw - 2;
        uint4 v = {0u,0u,0u,0u};
        if ((unsigned)ih < 32u && (unsigned)iw < 32u){
          v = *(const uint4*)&fin[(((n*32+ih)*32 + iw)<<6) + cc + ci0];
          unsigned short* hp = (unsigned short*)&v;
          #pragma unroll
          for (int jj=0;jj<8;jj++){
            int c = cc + ci0 + jj;
            hp[jj] = cvt_bf16(lrelu(bf2f(hp[jj])*gmA[c]+btA[c]));
          }
        }
        *(uint4*)&tile[cell*40 + (s2<<3)] = v;
      }
    }
    __syncthreads();
    const unsigned short* bp[2];
    #pragma unroll
    for (int nt=0;nt<2;nt++)
      bp[nt] = wbP + ((((cw*2+nt)*25)*2 + ccg)<<9) + lane*8;   // +tap*1024
    short8v bq[2][4];                       // 4-deep static prefetch ring
    #pragma unroll
    for (int p=0;p<4;p++)
      #pragma unroll
      for (int nt=0;nt<2;nt++) bq[nt][p] = *(const short8v*)(bp[nt] + (p<<10));
    #pragma unroll
    for (int tap=0; tap<25; tap++){
      const int kh = tap/5, kw = tap - kh*5;       // compile-time under unroll
      const int aoff = kh*36 + kw;
      short8v a[4];
      #pragma unroll
      for (int mt=0;mt<4;mt++){
        int cell = cellb[mt] + aoff;
        int q2 = q ^ ((cell>>3)&1);
        a[mt] = *(const short8v*)&tile[cell*40 + q2*8];
      }
      #pragma unroll
      for (int mt=0;mt<4;mt++)
        #pragma unroll
        for (int nt=0;nt<2;nt++)
          acc[mt][nt] = __builtin_amdgcn_mfma_f32_16x16x32_bf16(a[mt], bq[nt][tap&3], acc[mt][nt], 0,0,0);
      if (tap+4 < 25){
        #pragma unroll
        for (int nt=0;nt<2;nt++) bq[nt][tap&3] = *(const short8v*)(bp[nt] + ((tap+4)<<10));
      }
    }
  }
  #pragma unroll
  for (int nt=0;nt<2;nt++){
    int co = cw*32 + nt*16 + l16;
    float s=0.f, qq=0.f;
    #pragma unroll
    for (int mt=0;mt<4;mt++)
      #pragma unroll
      for (int e=0;e<4;e++){ float xv = acc[mt][nt][e]; s += xv; qq += xv*xv; }
    s  += __shfl_xor(s,16,64);  s  += __shfl_xor(s,32,64);
    qq += __shfl_xor(qq,16,64); qq += __shfl_xor(qq,32,64);
    if (q == 0){
      atomicAdd(&S2[n*128 + co], s);
      atomicAdd(&Q2[n*128 + co], qq);
    }
    #pragma unroll
    for (int mt=0;mt<4;mt++)
      #pragma unroll
      for (int e=0;e<4;e++){
        int px = half*128 + rw*64 + mt*16 + q*4 + e;
        fout[((n<<8) + px)*128 + co] = cvt_bf16(acc[mt][nt][e]);
      }
  }
}

// ---- conv3: Mb=64 x Nb=128, grid (256,2) x 512thr. 4-deep B ring + slot swizzle.
__global__ __launch_bounds__(512) void conv3_k(const unsigned short* __restrict__ fin,
                                               const unsigned short* __restrict__ wbP,
                                               const float* __restrict__ S2, const float* __restrict__ Q2,
                                               const float* __restrict__ g2, const float* __restrict__ be2,
                                               const float* __restrict__ g, const float* __restrict__ be,
                                               unsigned short* __restrict__ fout){
  const int t = threadIdx.x, n = blockIdx.x, co0 = blockIdx.y<<7;
  const int w = t>>6, lane = t&63, q = lane>>4, l16 = lane&15;
  const int rw = w&1, cw = w>>1;           // rw 0..1, cw 0..3
  __shared__ __align__(16) unsigned short tile[361*40];   // 28.9 KB
  __shared__ float gmA[128], btA[128];
  __shared__ float SQs[2][128], SQq[2][128];
  if (t < 128){
    float S = S2[n*128+t], Q = Q2[n*128+t];
    float mu = S*(1.f/256.f), var = fmaxf(Q*(1.f/256.f) - mu*mu, 0.f);
    float r = rsqrtf(var+EPSF)*g2[t];
    gmA[t] = r; btA[t] = be2[t] - mu*r;
  }
  __syncthreads();
  floatx4 acc[2][2];
  #pragma unroll
  for (int mt=0;mt<2;mt++)
    #pragma unroll
    for (int nt=0;nt<2;nt++) acc[mt][nt] = (floatx4){0.f,0.f,0.f,0.f};
  int cellb[2];
  #pragma unroll
  for (int mt=0;mt<2;mt++){
    int r = rw*32 + mt*16 + l16;
    int oh = r>>3, ow = r&7;
    cellb[mt] = (2*oh)*19 + 2*ow;
  }
  for (int ccg = 0; ccg < 4; ccg++){
    const int cc = ccg<<5;
    if (ccg) __syncthreads();
    #pragma unroll
    for (int it=0; it<3; it++){
      int idx = it*512 + t;
      if (idx < 1444){
        int cell = idx>>2, s = idx&3;
        int s2 = s ^ ((cell>>3)&1);            // slot swizzle
        int ci0 = s<<3;
        int tih = cell/19, tiw = cell - tih*19;
        int ih = tih - 2, iw = tiw - 2;
        uint4 v = {0u,0u,0u,0u};
        if ((unsigned)ih < 16u && (unsigned)iw < 16u){
          v = *(const uint4*)&fin[(((n*16+ih)*16 + iw)<<7) + cc + ci0];
          unsigned short* hp = (unsigned short*)&v;
          #pragma unroll
          for (int jj=0;jj<8;jj++){
            int c = cc + ci0 + jj;
            hp[jj] = cvt_bf16(lrelu(bf2f(hp[jj])*gmA[c]+btA[c]));
          }
        }
        *(uint4*)&tile[cell*40 + (s2<<3)] = v;
      }
    }
    __syncthreads();
    const unsigned short* bp[2];
    #pragma unroll
    for (int nt=0;nt<2;nt++)
      bp[nt] = wbP + (((((co0>>4)+cw*2+nt)*25)*4 + ccg)<<9) + lane*8;  // +tap*2048
    short8v bq[2][4];                       // 4-deep static prefetch ring
    #pragma unroll
    for (int p=0;p<4;p++)
      #pragma unroll
      for (int nt=0;nt<2;nt++) bq[nt][p] = *(const short8v*)(bp[nt] + (p<<11));
    #pragma unroll
    for (int tap=0; tap<25; tap++){
      const int kh = tap/5, kw = tap - kh*5;
      const int aoff = kh*19 + kw;
      short8v a[2];
      #pragma unroll
      for (int mt=0;mt<2;mt++){
        int cell = cellb[mt] + aoff;
        int q2 = q ^ ((cell>>3)&1);
        a[mt] = *(const short8v*)&tile[cell*40 + q2*8];
      }
      #pragma unroll
      for (int mt=0;mt<2;mt++)
        #pragma unroll
        for (int nt=0;nt<2;nt++)
          acc[mt][nt] = __builtin_amdgcn_mfma_f32_16x16x32_bf16(a[mt], bq[nt][tap&3], acc[mt][nt], 0,0,0);
      if (tap+4 < 25){
        #pragma unroll
        for (int nt=0;nt<2;nt++) bq[nt][tap&3] = *(const short8v*)(bp[nt] + ((tap+4)<<11));
      }
    }
  }
  #pragma unroll
  for (int nt=0;nt<2;nt++){
    int lcol = cw*32 + nt*16 + l16;
    float s=0.f, qq=0.f;
    #pragma unroll
    for (int mt=0;mt<2;mt++)
      #pragma unroll
      for (int e=0;e<4;e++){ float xv = acc[mt][nt][e]; s += xv; qq += xv*xv; }
    s  += __shfl_xor(s,16,64);  s  += __shfl_xor(s,32,64);
    qq += __shfl_xor(qq,16,64); qq += __shfl_xor(qq,32,64);
    if (q == 0){ SQs[rw][lcol] = s; SQq[rw][lcol] = qq; }
  }
  __syncthreads();
  #pragma unroll
  for (int nt=0;nt<2;nt++){
    int lcol = cw*32 + nt*16 + l16, co = co0 + lcol;
    float S = SQs[0][lcol] + SQs[1][lcol];
    float Q = SQq[0][lcol] + SQq[1][lcol];
    float mu = S*(1.f/64.f), var = fmaxf(Q*(1.f/64.f) - mu*mu, 0.f);
    float gmv = rsqrtf(var+EPSF)*g[co];
    float btv = be[co] - mu*gmv;
    #pragma unroll
    for (int mt=0;mt<2;mt++)
      #pragma unroll
      for (int e=0;e<4;e++){
        int row = rw*32 + mt*16 + q*4 + e;
        fout[((n<<6) + row)*256 + co] = cvt_bf16(lrelu(acc[mt][nt][e]*gmv+btv));
      }
  }
}

// ---- conv4: Mb=32 (2 images) x Nb=64, grid (128,4). 4-deep B ring + slot swizzle.
__global__ __launch_bounds__(256) void conv4_k(const unsigned short* __restrict__ fin,
                                               const unsigned short* __restrict__ wbP,
                                               const float* __restrict__ g, const float* __restrict__ be,
                                               float* __restrict__ feat, unsigned short* __restrict__ featb){
  const int t = threadIdx.x;
  const int n0 = blockIdx.x << 1, co0 = blockIdx.y << 6;
  const int w = t>>6, lane = t&63, q = lane>>4, l16 = lane&15;
  const int rw = w&1, cw = w>>1;
  __shared__ __align__(16) unsigned short tile[2*81*40];
  floatx4 acc[2];
  acc[0] = (floatx4){0.f,0.f,0.f,0.f};
  acc[1] = (floatx4){0.f,0.f,0.f,0.f};
  const int oh = l16>>2, ow = l16&3;
  const int cellb = (2*oh)*9 + 2*ow;
  for (int ccg = 0; ccg < 8; ccg++){
    const int cc = ccg<<5;
    if (ccg) __syncthreads();
    #pragma unroll
    for (int it=0; it<3; it++){
      int idx = it*256 + t;
      if (idx < 648){
        int img = idx >= 324 ? 1 : 0;
        int rem = idx - img*324;
        int cell = rem>>2, s = rem&3;
        int fc = img*81 + cell;
        int s2 = s ^ ((fc>>3)&1);              // slot swizzle
        int ci0 = s<<3;
        int tih = cell/9, tiw = cell - tih*9;
        int ih = tih - 1, iw = tiw - 1;
        uint4 v = {0u,0u,0u,0u};
        if ((unsigned)ih < 8u && (unsigned)iw < 8u)
          v = *(const uint4*)&fin[((((n0+img)*8+ih)*8 + iw)<<8) + cc + ci0];
        *(uint4*)&tile[fc*40 + (s2<<3)] = v;
      }
    }
    __syncthreads();
    const unsigned short* bp[2];
    #pragma unroll
    for (int nt=0;nt<2;nt++)
      bp[nt] = wbP + (((((co0>>4)+cw*2+nt)*9)*8 + ccg)<<9) + lane*8;  // +tap*4096
    short8v bq[2][4];
    #pragma unroll
    for (int p=0;p<4;p++)
      #pragma unroll
      for (int nt=0;nt<2;nt++) bq[nt][p] = *(const short8v*)(bp[nt] + (p<<12));
    #pragma unroll
    for (int tap=0; tap<9; tap++){
      const int kh = tap/3, kw = tap - kh*3;
      int fc = rw*81 + cellb + kh*9 + kw;
      int q2 = q ^ ((fc>>3)&1);
      short8v a = *(const short8v*)&tile[fc*40 + q2*8];
      #pragma unroll
      for (int nt=0;nt<2;nt++)
        acc[nt] = __builtin_amdgcn_mfma_f32_16x16x32_bf16(a, bq[nt][tap&3], acc[nt], 0,0,0);
      if (tap+4 < 9){
        #pragma unroll
        for (int nt=0;nt<2;nt++) bq[nt][tap&3] = *(const short8v*)(bp[nt] + ((tap+4)<<12));
      }
    }
  }
  const int nn = n0 + rw;
  #pragma unroll
  for (int nt=0;nt<2;nt++){
    int co = co0 + cw*32 + nt*16 + l16;
    float s=0.f, qq=0.f;
    #pragma unroll
    for (int e=0;e<4;e++){ float xv = acc[nt][e]; s += xv; qq += xv*xv; }
    s  += __shfl_xor(s,16,64);  s  += __shfl_xor(s,32,64);
    qq += __shfl_xor(qq,16,64); qq += __shfl_xor(qq,32,64);
    float mu = s*(1.f/16.f), var = fmaxf(qq*(1.f/16.f) - mu*mu, 0.f);
    float gmv = rsqrtf(var+EPSF)*g[co];
    float btv = be[co] - mu*gmv;
    #pragma unroll
    for (int e=0;e<4;e++){
      int px = q*4 + e;
      float vv = lrelu(acc[nt][e]*gmv+btv);
      feat [(nn<<12) + (co<<4) + px] = vv;
      featb[(nn<<12) + (co<<4) + px] = cvt_bf16(vv);
    }
  }
}

// ---- gemmM MFMA, LDS-less: Cp[z] = featb(256x4096 bf16) @ Tp(packed bf16), ksplit 8x512.
__global__ __launch_bounds__(256) void gemmM_k(const unsigned short* __restrict__ A,
                                               const unsigned short* __restrict__ Tp,
                                               float* __restrict__ Cp){
  const int t = threadIdx.x;
  const int n0 = blockIdx.x<<7, b0 = blockIdx.y<<7, k0 = blockIdx.z<<9;
  const int w = t>>6, lane = t&63, q = lane>>4, l16 = lane&15;
  const int rw = w&1, cw = w>>1;
  floatx4 acc[4][4];
  #pragma unroll
  for (int mt=0;mt<4;mt++)
    #pragma unroll
    for (int nt=0;nt<4;nt++) acc[mt][nt] = (floatx4){0.f,0.f,0.f,0.f};
  const unsigned short* Ab[4];
  const unsigned short* Bb[4];
  #pragma unroll
  for (int mt=0;mt<4;mt++)
    Ab[mt] = A + (b0 + (rw<<6) + (mt<<4) + l16)*4096 + k0 + (q<<3);
  #pragma unroll
  for (int nt=0;nt<4;nt++)
    Bb[nt] = Tp + ((((n0>>4) + (cw<<2) + nt)*128 + (k0>>5))*64 + lane)*8;
  #pragma unroll 4
  for (int kt=0; kt<16; kt++){
    short8v af[4], bfr[4];
    #pragma unroll
    for (int mt=0;mt<4;mt++) af[mt] = *(const short8v*)(Ab[mt] + kt*32);
    #pragma unroll
    for (int nt=0;nt<4;nt++) bfr[nt] = *(const short8v*)(Bb[nt] + kt*512);
    #pragma unroll
    for (int mt=0;mt<4;mt++)
      #pragma unroll
      for (int nt=0;nt<4;nt++)
        acc[mt][nt] = __builtin_amdgcn_mfma_f32_16x16x32_bf16(af[mt], bfr[nt], acc[mt][nt], 0,0,0);
  }
  float* C = Cp + blockIdx.z * 819200;
  #pragma unroll
  for (int mt=0;mt<4;mt++)
    #pragma unroll
    for (int nt=0;nt<4;nt++)
      #pragma unroll
      for (int e=0;e<4;e++){
        int row = b0 + (rw<<6) + (mt<<4) + (q<<2) + e;
        int col = n0 + (cw<<6) + (nt<<4) + l16;
        C[row*3200 + col] = acc[mt][nt][e];
      }
}

// reduce 8 partials -> Mh f16, rows padded [i][o][56] (16B-aligned rows for pair_k uint4 loads)
__global__ __launch_bounds__(256) void reduceM_k(const float* __restrict__ Cp, __half* __restrict__ Mh){
  int idx = blockIdx.x*256 + threadIdx.x;
  if (idx >= 917504) return;            // 256 * 3584
  int i = idx / 3584, r = idx - i*3584;
  int o = r / 56, k = r - o*56;
  float v = 0.f;
  if (k < 50){
    int src = i*3200 + o*50 + k;
    #pragma unroll
    for (int s = 0; s < 8; s++) v += Cp[s*819200 + src];
  }
  Mh[idx] = __float2half(v);
}

// ---- pairwise via packed f16, rows 56 halfs = 7 uint4 (zero-padded tail contributes 0)
__global__ __launch_bounds__(256) void pair_k(const __half* __restrict__ Mh,
                                              float* __restrict__ ob, unsigned short* __restrict__ obb){
  const int j = blockIdx.x, t = threadIdx.x;
  __shared__ __align__(16) __half2 Mj[1792];   // 64 o x 28 h2 = 7168 B
  __shared__ float red[256];
  for (int k=t; k<448; k+=256) ((uint4*)Mj)[k] = ((const uint4*)&Mh[j*3584])[k];
  __syncthreads();
  const int o = t & 63, ss = t >> 6;
  const uint4* mjp4 = (const uint4*)&Mj[o*28];
  float sum = 0.f;
  for (int i = ss<<6; i < (ss<<6)+64; i++){
    const uint4* mip4 = (const uint4*)&Mh[i*3584 + o*56];
    __half2 acch = __float2half2_rn(0.f);
    #pragma unroll
    for (int u=0;u<7;u++){
      uint4 av = mip4[u], bv = mjp4[u];
      const __half2* ah = (const __half2*)&av;
      const __half2* bh = (const __half2*)&bv;
      #pragma unroll
      for (int e=0;e<4;e++)
        acch = __hadd2(acch, __habs2(__hsub2(ah[e], bh[e])));
    }
    float dsum = __low2float(acch) + __high2float(acch);
    sum += __expf(-dsum);
  }
  red[(o<<2)+ss] = sum;
  __syncthreads();
  if (t < 64){
    float v = red[t<<2] + red[(t<<2)+1] + red[(t<<2)+2] + red[(t<<2)+3] - 1.0f;
    ob[(j<<6)+t] = v;
    obb[(j<<6)+t] = cvt_bf16(v);
  }
}

// ---- gemmFC MFMA, LDS-less: yp[z] = mb(256x4160 bf16) @ Wp(packed bf16)^T, ksplit 13x320.
__global__ __launch_bounds__(256) void gemmFC_k(const unsigned short* __restrict__ featb,
                                                const unsigned short* __restrict__ obb,
                                                const unsigned short* __restrict__ Wp,
                                                float* __restrict__ Cp){
  const int t = threadIdx.x;
  const int o0 = blockIdx.x<<7, b0 = blockIdx.y<<7, kz = blockIdx.z;   // k0 = kz*320
  const int w = t>>6, lane = t&63, q = lane>>4, l16 = lane&15;
  const int rw = w&1, cw = w>>1;
  floatx4 acc[4][4];
  #pragma unroll
  for (int mt=0;mt<4;mt++)
    #pragma unroll
    for (int nt=0;nt<4;nt++) acc[mt][nt] = (floatx4){0.f,0.f,0.f,0.f};
  int rowb[4];
  #pragma unroll
  for (int mt=0;mt<4;mt++) rowb[mt] = b0 + (rw<<6) + (mt<<4) + l16;
  const unsigned short* Bb[4];
  #pragma unroll
  for (int nt=0;nt<4;nt++)
    Bb[nt] = Wp + ((((o0>>4) + (cw<<2) + nt)*130 + kz*10)*64 + lane)*8;
  #pragma unroll 2
  for (int kt=0; kt<10; kt++){
    int k = kz*320 + kt*32 + (q<<3);
    short8v af[4], bfr[4];
    #pragma unroll
    for (int mt=0;mt<4;mt++)
      af[mt] = (k < 4096) ? *(const short8v*)&featb[rowb[mt]*4096 + k]
                          : *(const short8v*)&obb[rowb[mt]*64 + (k-4096)];
    #pragma unroll
    for (int nt=0;nt<4;nt++) bfr[nt] = *(const short8v*)(Bb[nt] + kt*512);
    #pragma unroll
    for (int mt=0;mt<4;mt++)
      #pragma unroll
      for (int nt=0;nt<4;nt++)
        acc[mt][nt] = __builtin_amdgcn_mfma_f32_16x16x32_bf16(af[mt], bfr[nt], acc[mt][nt], 0,0,0);
  }
  float* C = Cp + blockIdx.z * 256000;
  #pragma unroll
  for (int mt=0;mt<4;mt++)
    #pragma unroll
    for (int nt=0;nt<4;nt++)
      #pragma unroll
      for (int e=0;e<4;e++){
        int row = b0 + (rw<<6) + (mt<<4) + (q<<2) + e;
        int col = o0 + (cw<<6) + (nt<<4) + l16;
        if (col < 1000) C[row*1000 + col] = acc[mt][nt][e];
      }
}

__global__ __launch_bounds__(256) void reduceY_k(const float* __restrict__ Cp, const float* __restrict__ bias,
                                                 float* __restrict__ y){
  int idx = blockIdx.x * 256 + threadIdx.x;
  if (idx >= 256000) return;
  int o = idx % 1000;
  float r = bias[o];
  #pragma unroll
  for (int s = 0; s < 13; s++) r += Cp[s*256000 + idx];
  y[idx] = r;
}

extern "C" void kernel_launch(void* const* d_in, const int* in_sizes, int n_in,
                              void* d_out, int out_size, void* d_ws, size_t ws_size,
                              hipStream_t stream){
  const float* x   = (const float*)d_in[0];
  const float* w1  = (const float*)d_in[1];
  const float* g1  = (const float*)d_in[3];
  const float* be1 = (const float*)d_in[4];
  const float* w2  = (const float*)d_in[5];
  const float* g2  = (const float*)d_in[7];
  const float* be2 = (const float*)d_in[8];
  const float* w3  = (const float*)d_in[9];
  const float* g3  = (const float*)d_in[11];
  const float* be3 = (const float*)d_in[12];
  const float* w4  = (const float*)d_in[13];
  const float* g4  = (const float*)d_in[15];
  const float* be4 = (const float*)d_in[16];
  const float* T   = (const float*)d_in[17];
  const float* fcw = (const float*)d_in[18];
  const float* fcb = (const float*)d_in[19];
  float* out = (float*)d_out;
  float* ws  = (float*)d_ws;

  // workspace (float units)
  unsigned short* f1raw = (unsigned short*)ws;               // 8,388,608 fl
  // Tp aliases dead f1raw after conv2: 13,107,200 shorts = 6,553,600 fl <= 8,388,608 ✓
  unsigned short* Tp    = (unsigned short*)ws;
  unsigned short* f2    = (unsigned short*)(ws + 8388608);   // 4,194,304 fl
  unsigned short* f3    = (unsigned short*)(ws + 12582912);  // 2,097,152 fl
  unsigned short* featb = (unsigned short*)(ws + 14680064);  //   524,288 fl
  unsigned short* wb1   = (unsigned short*)(ws + 15204352);  //     4,096 fl
  unsigned short* wb2   = (unsigned short*)(ws + 15208448);  //   102,400 fl
  unsigned short* wb3   = (unsigned short*)(ws + 15310848);  //   409,600 fl
  unsigned short* wb4   = (unsigned short*)(ws + 15720448);  //   294,912 fl
  float* S1    = ws + 16015360;                              //    16,384
  float* Q1    = ws + 16031744;                              //    16,384
  float* S2    = ws + 16048128;                              //    32,768
  float* Q2    = ws + 16080896;                              //    32,768  (end 16,113,664)
  float* Mp    = ws + 16113664;                              // 6,553,600
  // Wp aliases Mp (dead after reduceM): 4,259,840 shorts = 2,129,920 fl <= 6,553,600 ✓
  unsigned short* Wp  = (unsigned short*)(ws + 16113664);
  __half* Mh   = (__half*)(ws + 22667264);                   //   458,752 fl (256x3584 halfs, rows padded to 56)
  float* obuf  = ws + 23126016;                              //    16,384
  unsigned short* obb = (unsigned short*)(ws + 23142400);    //     8,192 fl
  float* yp    = ws + 23150592;                              // 3,328,000 (end 26,478,592 fl)
  float* feat  = out;
  float* y     = out + 1048576;

  prep_k<<<dim3(6720), 256, 0, stream>>>(w1, w2, w3, w4, wb1, wb2, wb3, wb4, S1);

  conv1_k<<<dim3(512),     256, 0, stream>>>(x, wb1, S1, Q1, f1raw);
  conv2_k<<<dim3(512),     512, 0, stream>>>(f1raw, wb2, S1, Q1, g1, be1, S2, Q2, f2);
  packT_k<<<dim3(3200),    256, 0, stream>>>(T, Tp);
  conv3_k<<<dim3(256, 2),  512, 0, stream>>>(f2, wb3, S2, Q2, g2, be2, g3, be3, f3);
  conv4_k<<<dim3(128, 4),  256, 0, stream>>>(f3, wb4, g4, be4, feat, featb);

  gemmM_k  <<<dim3(25, 2, 8),  256, 0, stream>>>(featb, Tp, Mp);
  reduceM_k<<<dim3(3584),      256, 0, stream>>>(Mp, Mh);
  packW_k  <<<dim3(2080),      256, 0, stream>>>(fcw, Wp);
  pair_k   <<<dim3(256),       256, 0, stream>>>(Mh, obuf, obb);
  gemmFC_k <<<dim3(8, 2, 13),  256, 0, stream>>>(featb, obb, Wp, yp);
  reduceY_k<<<dim3(1000),      256, 0, stream>>>(yp, fcb, y);
}

// Round 8
// 354.248 us; speedup vs baseline: 1.1127x; 1.1127x over previous
//
#include <hip/hip_runtime.h>
#include <hip/hip_fp16.h>
#include <math.h>

#define EPSF 1e-5f

typedef __attribute__((ext_vector_type(4))) float  floatx4;
typedef __attribute__((ext_vector_type(4))) short  short4v;
typedef __attribute__((ext_vector_type(8))) short  short8v;

__device__ __forceinline__ unsigned short cvt_bf16(float f){
  unsigned u = __float_as_uint(f);
  unsigned r = (u + 0x7FFFu + ((u >> 16) & 1u)) >> 16;
  return (unsigned short)r;
}
__device__ __forceinline__ float bf2f(unsigned short h){
  return __uint_as_float(((unsigned)h) << 16);
}
__device__ __forceinline__ short8v ld_frag(const unsigned short* p){
  short4v lo = *(const short4v*)p;
  short4v hi = *(const short4v*)(p + 4);
  return __builtin_shufflevector(lo, hi, 0,1,2,3,4,5,6,7);
}
__device__ __forceinline__ float lrelu(float x){ return x >= 0.f ? x : 0.2f*x; }

// ---- merged prep. Weights fragment-packed: [co16grp][tap][ccgrp][lane64][8]
// b-frag lane mapping (16x16x32): co_local = lane&15, k = (lane>>4)*8 + j.
__global__ __launch_bounds__(256) void prep_k(const float* __restrict__ w1, const float* __restrict__ w2,
                                              const float* __restrict__ w3, const float* __restrict__ w4,
                                              unsigned short* __restrict__ wb1, unsigned short* __restrict__ wb2,
                                              unsigned short* __restrict__ wb3, unsigned short* __restrict__ wb4,
                                              float* __restrict__ SQ){
  int b = blockIdx.x, t = threadIdx.x;
  if (b < 32){                       // conv1: 4 grp x 4 ks x 512; k=(kh*6+kw)*4+ci over K=128
    int idx = b*256 + t;             // 8192 shorts
    int j = idx&7, lane = (idx>>3)&63, ks = (idx>>9)&3, grp = idx>>11;
    int co = grp*16 + (lane&15);
    int k = ks*32 + ((lane>>4)<<3) + j;
    int tap6 = k>>2, ci = k&3;
    int kh = tap6/6, kw = tap6 - kh*6;
    float v = 0.f;
    if (ci < 3 && kh < 5 && kw < 5) v = w1[(co*3 + ci)*25 + kh*5 + kw];
    wb1[idx] = cvt_bf16(v);
  } else if (b < 832){               // conv2: 8 grp x 25 tap x 2 ccg x 512 = 204800
    int idx = (b-32)*256 + t;
    int grp = idx/25600, rem = idx - grp*25600;
    int tap = rem/1024, rem2 = rem - tap*1024;
    int ccg = rem2>>9, lane = (rem2>>3)&63, j = rem2&7;
    int co = grp*16 + (lane&15);
    int ci = ccg*32 + ((lane>>4)<<3) + j;
    wb2[idx] = cvt_bf16(w2[(co*64 + ci)*25 + tap]);
  } else if (b < 4032){              // conv3: 16 grp x 25 tap x 4 ccg x 512 = 819200
    int idx = (b-832)*256 + t;
    int grp = idx/51200, rem = idx - grp*51200;
    int tap = rem/2048, rem2 = rem - tap*2048;
    int ccg = rem2>>9, lane = (rem2>>3)&63, j = rem2&7;
    int co = grp*16 + (lane&15);
    int ci = ccg*32 + ((lane>>4)<<3) + j;
    wb3[idx] = cvt_bf16(w3[(co*128 + ci)*25 + tap]);
  } else if (b < 6336){              // conv4: 16 grp x 9 tap x 8 ccg x 512 = 589824
    int idx = (b-4032)*256 + t;
    int grp = idx/36864, rem = idx - grp*36864;
    int tap = rem/4096, rem2 = rem - tap*4096;
    int ccg = rem2>>9, lane = (rem2>>3)&63, j = rem2&7;
    int co = grp*16 + (lane&15);
    int ci = ccg*32 + ((lane>>4)<<3) + j;
    wb4[idx] = cvt_bf16(w4[(co*256 + ci)*9 + tap]);
  } else {                           // zero S1/Q1/S2/Q2 (98304 floats)
    int idx = (b-6336)*256 + t;
    SQ[idx] = 0.f;
  }
}

// ---- packT_k: T (4096x3200 fp32) -> bf16 MFMA b-fragment layout.
// Tp: [ngrp(200)][ktile(128)][lane(64)][8]; aliases dead f1raw (launched after conv2).
__global__ __launch_bounds__(256) void packT_k(const float* __restrict__ T,
                                               unsigned short* __restrict__ Tp){
  const int b = blockIdx.x, t = threadIdx.x;
  __shared__ float tile[32][133];
  const int nb = b % 25, kt = b / 25;
  const int n0 = nb*128, k0 = kt*32;
  #pragma unroll
  for (int m=0;m<4;m++){
    int idx = m*256 + t;
    int row = idx>>5, c4 = (idx&31)<<2;
    const float4 v = *(const float4*)&T[(k0+row)*3200 + n0 + c4];
    tile[row][c4]   = v.x; tile[row][c4+1] = v.y;
    tile[row][c4+2] = v.z; tile[row][c4+3] = v.w;
  }
  __syncthreads();
  #pragma unroll
  for (int m=0;m<2;m++){
    int c = m*256 + t;
    int ngl = c>>6, lane = c&63, q = lane>>4, r = lane&15;
    unsigned short h[8];
    #pragma unroll
    for (int j=0;j<8;j++) h[j] = cvt_bf16(tile[q*8+j][ngl*16 + r]);
    *(uint4*)&Tp[(((nb*8 + ngl)*128 + kt)*64 + lane)*8] = *(const uint4*)h;
  }
}

// ---- packW_k: fcw (1000x4160 fp32) -> bf16 b-fragment layout. Aliases Mp (after reduceM).
__global__ __launch_bounds__(256) void packW_k(const float* __restrict__ W,
                                               unsigned short* __restrict__ Wp){
  int idx = blockIdx.x*256 + threadIdx.x;   // 532480 chunks of 8
  int lane = idx & 63, rem = idx >> 6;
  int kt = rem % 130, ng = rem / 130;
  int q = lane>>4, r = lane&15;
  int orow = ng*16 + r, k = kt*32 + (q<<3);
  unsigned short h[8] = {0,0,0,0,0,0,0,0};
  if (orow < 1000){
    float4 v0 = *(const float4*)&W[orow*4160 + k];
    float4 v1 = *(const float4*)&W[orow*4160 + k + 4];
    h[0]=cvt_bf16(v0.x); h[1]=cvt_bf16(v0.y); h[2]=cvt_bf16(v0.z); h[3]=cvt_bf16(v0.w);
    h[4]=cvt_bf16(v1.x); h[5]=cvt_bf16(v1.y); h[6]=cvt_bf16(v1.z); h[7]=cvt_bf16(v1.w);
  }
  *(uint4*)&Wp[idx*8] = *(const uint4*)h;
}

// ---- conv1: half-image blocks (grid 512). Raw f1 + S1/Q1 atomics.
// img has 36 rows: row 35 is an always-zero guard row (kh=5 pad taps land there).
__global__ __launch_bounds__(256) void conv1_k(const float* __restrict__ x, const unsigned short* __restrict__ wb1P,
                                               float* __restrict__ S1, float* __restrict__ Q1,
                                               unsigned short* __restrict__ f1raw){
  const int t = threadIdx.x, n = blockIdx.x>>1, half = blockIdx.x&1;
  const int w = t>>6, lane = t&63, q = lane>>4, l16 = lane&15;
  __shared__ __align__(16) unsigned short img[36*68*4];   // [tih][iw+2][ci] 19.6 KB
  short8v bf[4][4];
  #pragma unroll
  for (int nt=0;nt<4;nt++)
    #pragma unroll
    for (int ks=0;ks<4;ks++)
      bf[nt][ks] = *(const short8v*)&wb1P[((nt*4+ks)*64 + lane)*8];
  for (int i=t; i<4896; i+=256) ((unsigned*)img)[i] = 0u;
  __syncthreads();
  for (int idx=t; idx<1680; idx+=256){
    int ci = idx/560, rem = idx - ci*560;
    int tih = rem>>4, iw4 = (rem&15)<<2;
    int ih = half*32 - 2 + tih;
    if ((unsigned)ih < 64u){
      float4 v = *(const float4*)&x[((n*3+ci)<<12) + (ih<<6) + iw4];
      int base = (tih*68 + iw4 + 2)*4 + ci;
      img[base]    = cvt_bf16(v.x);
      img[base+4]  = cvt_bf16(v.y);
      img[base+8]  = cvt_bf16(v.z);
      img[base+12] = cvt_bf16(v.w);
    }
  }
  __syncthreads();
  floatx4 acc[8][4];
  #pragma unroll
  for (int mi=0;mi<8;mi++)
    #pragma unroll
    for (int nt=0;nt<4;nt++) acc[mi][nt] = (floatx4){0.f,0.f,0.f,0.f};
  #pragma unroll
  for (int mi=0; mi<8; mi++){
    int r = w*8 + mi;                 // mtile 0..31 within half
    int ohl = r>>1, ow = ((r&1)<<4) + l16;
    #pragma unroll
    for (int ks=0; ks<4; ks++){
      int t0 = ks*8 + 2*q;
      int kh = t0/6, kw = t0 - kh*6;
      short8v a = ld_frag(&img[((ohl*2+kh)*68 + ow*2 + kw)*4]);
      #pragma unroll
      for (int nt=0; nt<4; nt++)
        acc[mi][nt] = __builtin_amdgcn_mfma_f32_16x16x32_bf16(a, bf[nt][ks], acc[mi][nt], 0,0,0);
    }
  }
  float sreg[4] = {0,0,0,0}, qreg[4] = {0,0,0,0};
  #pragma unroll
  for (int mi=0;mi<8;mi++){
    int r = w*8 + mi;
    #pragma unroll
    for (int nt=0;nt<4;nt++)
      #pragma unroll
      for (int e=0;e<4;e++){
        float v = acc[mi][nt][e];
        sreg[nt] += v; qreg[nt] += v*v;
        int px = half*512 + (r<<4) + (q<<2) + e;
        f1raw[(((n<<10)+px)<<6) + (nt<<4) + l16] = cvt_bf16(v);
      }
  }
  #pragma unroll
  for (int nt=0;nt<4;nt++){
    float s = sreg[nt], qq = qreg[nt];
    s  += __shfl_xor(s,16,64);  s  += __shfl_xor(s,32,64);
    qq += __shfl_xor(qq,16,64); qq += __shfl_xor(qq,32,64);
    if (q==0){
      atomicAdd(&S1[(n<<6) + (nt<<4) + l16], s);
      atomicAdd(&Q1[(n<<6) + (nt<<4) + l16], qq);
    }
  }
}

// ---- conv2: Mb=128 x Nb=128, grid 512 x 512thr. 4-deep B ring + slot swizzle.
__global__ __launch_bounds__(512) void conv2_k(const unsigned short* __restrict__ fin,
                                               const unsigned short* __restrict__ wbP,
                                               const float* __restrict__ S1, const float* __restrict__ Q1,
                                               const float* __restrict__ g1, const float* __restrict__ be1,
                                               float* __restrict__ S2, float* __restrict__ Q2,
                                               unsigned short* __restrict__ fout){
  const int t = threadIdx.x;
  const int n = blockIdx.x >> 1, half = blockIdx.x & 1;
  const int w = t>>6, lane = t&63, q = lane>>4, l16 = lane&15;
  const int rw = w&1, cw = w>>1;           // rw 0..1, cw 0..3
  __shared__ __align__(16) unsigned short tile[684*40];   // 19x36 cells, 54.7 KB
  __shared__ float gmA[64], btA[64];
  if (t < 64){
    float S = S1[(n<<6)+t], Q = Q1[(n<<6)+t];
    float mu = S*(1.f/1024.f), var = fmaxf(Q*(1.f/1024.f) - mu*mu, 0.f);
    float r = rsqrtf(var+EPSF)*g1[t];
    gmA[t] = r; btA[t] = be1[t] - mu*r;
  }
  __syncthreads();
  floatx4 acc[4][2];
  #pragma unroll
  for (int mt=0;mt<4;mt++)
    #pragma unroll
    for (int nt=0;nt<2;nt++) acc[mt][nt] = (floatx4){0.f,0.f,0.f,0.f};
  int cellb[4];
  #pragma unroll
  for (int mt=0;mt<4;mt++){
    int r = rw*64 + mt*16 + l16;
    int ohl = r>>4, ow = r&15;
    cellb[mt] = (2*ohl)*36 + 2*ow;
  }
  for (int ccg = 0; ccg < 2; ccg++){
    const int cc = ccg<<5;
    if (ccg) __syncthreads();
    #pragma unroll
    for (int it=0; it<6; it++){
      int idx = it*512 + t;
      if (idx < 2736){
        int cell = idx>>2, s = idx&3;
        int s2 = s ^ ((cell>>3)&1);            // slot swizzle
        int ci0 = s<<3;
        int tih = cell/36, tiw = cell - tih*36;
        int ih = half*16 + tih - 2, iw = tiw - 2;
        uint4 v = {0u,0u,0u,0u};
        if ((unsigned)ih < 32u && (unsigned)iw < 32u){
          v = *(const uint4*)&fin[(((n*32+ih)*32 + iw)<<6) + cc + ci0];
          unsigned short* hp = (unsigned short*)&v;
          #pragma unroll
          for (int jj=0;jj<8;jj++){
            int c = cc + ci0 + jj;
            hp[jj] = cvt_bf16(lrelu(bf2f(hp[jj])*gmA[c]+btA[c]));
          }
        }
        *(uint4*)&tile[cell*40 + (s2<<3)] = v;
      }
    }
    __syncthreads();
    const unsigned short* bp[2];
    #pragma unroll
    for (int nt=0;nt<2;nt++)
      bp[nt] = wbP + ((((cw*2+nt)*25)*2 + ccg)<<9) + lane*8;   // +tap*1024
    short8v bq[2][4];                       // 4-deep static prefetch ring
    #pragma unroll
    for (int p=0;p<4;p++)
      #pragma unroll
      for (int nt=0;nt<2;nt++) bq[nt][p] = *(const short8v*)(bp[nt] + (p<<10));
    #pragma unroll
    for (int tap=0; tap<25; tap++){
      const int kh = tap/5, kw = tap - kh*5;       // compile-time under unroll
      const int aoff = kh*36 + kw;
      short8v a[4];
      #pragma unroll
      for (int mt=0;mt<4;mt++){
        int cell = cellb[mt] + aoff;
        int q2 = q ^ ((cell>>3)&1);
        a[mt] = *(const short8v*)&tile[cell*40 + q2*8];
      }
      #pragma unroll
      for (int mt=0;mt<4;mt++)
        #pragma unroll
        for (int nt=0;nt<2;nt++)
          acc[mt][nt] = __builtin_amdgcn_mfma_f32_16x16x32_bf16(a[mt], bq[nt][tap&3], acc[mt][nt], 0,0,0);
      if (tap+4 < 25){
        #pragma unroll
        for (int nt=0;nt<2;nt++) bq[nt][tap&3] = *(const short8v*)(bp[nt] + ((tap+4)<<10));
      }
    }
  }
  #pragma unroll
  for (int nt=0;nt<2;nt++){
    int co = cw*32 + nt*16 + l16;
    float s=0.f, qq=0.f;
    #pragma unroll
    for (int mt=0;mt<4;mt++)
      #pragma unroll
      for (int e=0;e<4;e++){ float xv = acc[mt][nt][e]; s += xv; qq += xv*xv; }
    s  += __shfl_xor(s,16,64);  s  += __shfl_xor(s,32,64);
    qq += __shfl_xor(qq,16,64); qq += __shfl_xor(qq,32,64);
    if (q == 0){
      atomicAdd(&S2[n*128 + co], s);
      atomicAdd(&Q2[n*128 + co], qq);
    }
    #pragma unroll
    for (int mt=0;mt<4;mt++)
      #pragma unroll
      for (int e=0;e<4;e++){
        int px = half*128 + rw*64 + mt*16 + q*4 + e;
        fout[((n<<8) + px)*128 + co] = cvt_bf16(acc[mt][nt][e]);
      }
  }
}

// ---- conv3: Mb=64 x Nb=128, grid (256,2) x 512thr. 4-deep B ring + slot swizzle.
__global__ __launch_bounds__(512) void conv3_k(const unsigned short* __restrict__ fin,
                                               const unsigned short* __restrict__ wbP,
                                               const float* __restrict__ S2, const float* __restrict__ Q2,
                                               const float* __restrict__ g2, const float* __restrict__ be2,
                                               const float* __restrict__ g, const float* __restrict__ be,
                                               unsigned short* __restrict__ fout){
  const int t = threadIdx.x, n = blockIdx.x, co0 = blockIdx.y<<7;
  const int w = t>>6, lane = t&63, q = lane>>4, l16 = lane&15;
  const int rw = w&1, cw = w>>1;           // rw 0..1, cw 0..3
  __shared__ __align__(16) unsigned short tile[361*40];   // 28.9 KB
  __shared__ float gmA[128], btA[128];
  __shared__ float SQs[2][128], SQq[2][128];
  if (t < 128){
    float S = S2[n*128+t], Q = Q2[n*128+t];
    float mu = S*(1.f/256.f), var = fmaxf(Q*(1.f/256.f) - mu*mu, 0.f);
    float r = rsqrtf(var+EPSF)*g2[t];
    gmA[t] = r; btA[t] = be2[t] - mu*r;
  }
  __syncthreads();
  floatx4 acc[2][2];
  #pragma unroll
  for (int mt=0;mt<2;mt++)
    #pragma unroll
    for (int nt=0;nt<2;nt++) acc[mt][nt] = (floatx4){0.f,0.f,0.f,0.f};
  int cellb[2];
  #pragma unroll
  for (int mt=0;mt<2;mt++){
    int r = rw*32 + mt*16 + l16;
    int oh = r>>3, ow = r&7;
    cellb[mt] = (2*oh)*19 + 2*ow;
  }
  for (int ccg = 0; ccg < 4; ccg++){
    const int cc = ccg<<5;
    if (ccg) __syncthreads();
    #pragma unroll
    for (int it=0; it<3; it++){
      int idx = it*512 + t;
      if (idx < 1444){
        int cell = idx>>2, s = idx&3;
        int s2 = s ^ ((cell>>3)&1);            // slot swizzle
        int ci0 = s<<3;
        int tih = cell/19, tiw = cell - tih*19;
        int ih = tih - 2, iw = tiw - 2;
        uint4 v = {0u,0u,0u,0u};
        if ((unsigned)ih < 16u && (unsigned)iw < 16u){
          v = *(const uint4*)&fin[(((n*16+ih)*16 + iw)<<7) + cc + ci0];
          unsigned short* hp = (unsigned short*)&v;
          #pragma unroll
          for (int jj=0;jj<8;jj++){
            int c = cc + ci0 + jj;
            hp[jj] = cvt_bf16(lrelu(bf2f(hp[jj])*gmA[c]+btA[c]));
          }
        }
        *(uint4*)&tile[cell*40 + (s2<<3)] = v;
      }
    }
    __syncthreads();
    const unsigned short* bp[2];
    #pragma unroll
    for (int nt=0;nt<2;nt++)
      bp[nt] = wbP + (((((co0>>4)+cw*2+nt)*25)*4 + ccg)<<9) + lane*8;  // +tap*2048
    short8v bq[2][4];                       // 4-deep static prefetch ring
    #pragma unroll
    for (int p=0;p<4;p++)
      #pragma unroll
      for (int nt=0;nt<2;nt++) bq[nt][p] = *(const short8v*)(bp[nt] + (p<<11));
    #pragma unroll
    for (int tap=0; tap<25; tap++){
      const int kh = tap/5, kw = tap - kh*5;
      const int aoff = kh*19 + kw;
      short8v a[2];
      #pragma unroll
      for (int mt=0;mt<2;mt++){
        int cell = cellb[mt] + aoff;
        int q2 = q ^ ((cell>>3)&1);
        a[mt] = *(const short8v*)&tile[cell*40 + q2*8];
      }
      #pragma unroll
      for (int mt=0;mt<2;mt++)
        #pragma unroll
        for (int nt=0;nt<2;nt++)
          acc[mt][nt] = __builtin_amdgcn_mfma_f32_16x16x32_bf16(a[mt], bq[nt][tap&3], acc[mt][nt], 0,0,0);
      if (tap+4 < 25){
        #pragma unroll
        for (int nt=0;nt<2;nt++) bq[nt][tap&3] = *(const short8v*)(bp[nt] + ((tap+4)<<11));
      }
    }
  }
  #pragma unroll
  for (int nt=0;nt<2;nt++){
    int lcol = cw*32 + nt*16 + l16;
    float s=0.f, qq=0.f;
    #pragma unroll
    for (int mt=0;mt<2;mt++)
      #pragma unroll
      for (int e=0;e<4;e++){ float xv = acc[mt][nt][e]; s += xv; qq += xv*xv; }
    s  += __shfl_xor(s,16,64);  s  += __shfl_xor(s,32,64);
    qq += __shfl_xor(qq,16,64); qq += __shfl_xor(qq,32,64);
    if (q == 0){ SQs[rw][lcol] = s; SQq[rw][lcol] = qq; }
  }
  __syncthreads();
  #pragma unroll
  for (int nt=0;nt<2;nt++){
    int lcol = cw*32 + nt*16 + l16, co = co0 + lcol;
    float S = SQs[0][lcol] + SQs[1][lcol];
    float Q = SQq[0][lcol] + SQq[1][lcol];
    float mu = S*(1.f/64.f), var = fmaxf(Q*(1.f/64.f) - mu*mu, 0.f);
    float gmv = rsqrtf(var+EPSF)*g[co];
    float btv = be[co] - mu*gmv;
    #pragma unroll
    for (int mt=0;mt<2;mt++)
      #pragma unroll
      for (int e=0;e<4;e++){
        int row = rw*32 + mt*16 + q*4 + e;
        fout[((n<<6) + row)*256 + co] = cvt_bf16(lrelu(acc[mt][nt][e]*gmv+btv));
      }
  }
}

// ---- conv4: Mb=32 (2 images) x Nb=64, grid (128,4). 4-deep B ring + slot swizzle.
__global__ __launch_bounds__(256) void conv4_k(const unsigned short* __restrict__ fin,
                                               const unsigned short* __restrict__ wbP,
                                               const float* __restrict__ g, const float* __restrict__ be,
                                               float* __restrict__ feat, unsigned short* __restrict__ featb){
  const int t = threadIdx.x;
  const int n0 = blockIdx.x << 1, co0 = blockIdx.y << 6;
  const int w = t>>6, lane = t&63, q = lane>>4, l16 = lane&15;
  const int rw = w&1, cw = w>>1;
  __shared__ __align__(16) unsigned short tile[2*81*40];
  floatx4 acc[2];
  acc[0] = (floatx4){0.f,0.f,0.f,0.f};
  acc[1] = (floatx4){0.f,0.f,0.f,0.f};
  const int oh = l16>>2, ow = l16&3;
  const int cellb = (2*oh)*9 + 2*ow;
  for (int ccg = 0; ccg < 8; ccg++){
    const int cc = ccg<<5;
    if (ccg) __syncthreads();
    #pragma unroll
    for (int it=0; it<3; it++){
      int idx = it*256 + t;
      if (idx < 648){
        int img = idx >= 324 ? 1 : 0;
        int rem = idx - img*324;
        int cell = rem>>2, s = rem&3;
        int fc = img*81 + cell;
        int s2 = s ^ ((fc>>3)&1);              // slot swizzle
        int ci0 = s<<3;
        int tih = cell/9, tiw = cell - tih*9;
        int ih = tih - 1, iw = tiw - 1;
        uint4 v = {0u,0u,0u,0u};
        if ((unsigned)ih < 8u && (unsigned)iw < 8u)
          v = *(const uint4*)&fin[((((n0+img)*8+ih)*8 + iw)<<8) + cc + ci0];
        *(uint4*)&tile[fc*40 + (s2<<3)] = v;
      }
    }
    __syncthreads();
    const unsigned short* bp[2];
    #pragma unroll
    for (int nt=0;nt<2;nt++)
      bp[nt] = wbP + (((((co0>>4)+cw*2+nt)*9)*8 + ccg)<<9) + lane*8;  // +tap*4096
    short8v bq[2][4];
    #pragma unroll
    for (int p=0;p<4;p++)
      #pragma unroll
      for (int nt=0;nt<2;nt++) bq[nt][p] = *(const short8v*)(bp[nt] + (p<<12));
    #pragma unroll
    for (int tap=0; tap<9; tap++){
      const int kh = tap/3, kw = tap - kh*3;
      int fc = rw*81 + cellb + kh*9 + kw;
      int q2 = q ^ ((fc>>3)&1);
      short8v a = *(const short8v*)&tile[fc*40 + q2*8];
      #pragma unroll
      for (int nt=0;nt<2;nt++)
        acc[nt] = __builtin_amdgcn_mfma_f32_16x16x32_bf16(a, bq[nt][tap&3], acc[nt], 0,0,0);
      if (tap+4 < 9){
        #pragma unroll
        for (int nt=0;nt<2;nt++) bq[nt][tap&3] = *(const short8v*)(bp[nt] + ((tap+4)<<12));
      }
    }
  }
  const int nn = n0 + rw;
  #pragma unroll
  for (int nt=0;nt<2;nt++){
    int co = co0 + cw*32 + nt*16 + l16;
    float s=0.f, qq=0.f;
    #pragma unroll
    for (int e=0;e<4;e++){ float xv = acc[nt][e]; s += xv; qq += xv*xv; }
    s  += __shfl_xor(s,16,64);  s  += __shfl_xor(s,32,64);
    qq += __shfl_xor(qq,16,64); qq += __shfl_xor(qq,32,64);
    float mu = s*(1.f/16.f), var = fmaxf(qq*(1.f/16.f) - mu*mu, 0.f);
    float gmv = rsqrtf(var+EPSF)*g[co];
    float btv = be[co] - mu*gmv;
    #pragma unroll
    for (int e=0;e<4;e++){
      int px = q*4 + e;
      float vv = lrelu(acc[nt][e]*gmv+btv);
      feat [(nn<<12) + (co<<4) + px] = vv;
      featb[(nn<<12) + (co<<4) + px] = cvt_bf16(vv);
    }
  }
}

// ---- gemmM MFMA, LDS-less: Cp[z] = featb(256x4096 bf16) @ Tp(packed bf16), ksplit 8x512.
__global__ __launch_bounds__(256) void gemmM_k(const unsigned short* __restrict__ A,
                                               const unsigned short* __restrict__ Tp,
                                               float* __restrict__ Cp){
  const int t = threadIdx.x;
  const int n0 = blockIdx.x<<7, b0 = blockIdx.y<<7, k0 = blockIdx.z<<9;
  const int w = t>>6, lane = t&63, q = lane>>4, l16 = lane&15;
  const int rw = w&1, cw = w>>1;
  floatx4 acc[4][4];
  #pragma unroll
  for (int mt=0;mt<4;mt++)
    #pragma unroll
    for (int nt=0;nt<4;nt++) acc[mt][nt] = (floatx4){0.f,0.f,0.f,0.f};
  const unsigned short* Ab[4];
  const unsigned short* Bb[4];
  #pragma unroll
  for (int mt=0;mt<4;mt++)
    Ab[mt] = A + (b0 + (rw<<6) + (mt<<4) + l16)*4096 + k0 + (q<<3);
  #pragma unroll
  for (int nt=0;nt<4;nt++)
    Bb[nt] = Tp + ((((n0>>4) + (cw<<2) + nt)*128 + (k0>>5))*64 + lane)*8;
  #pragma unroll 4
  for (int kt=0; kt<16; kt++){
    short8v af[4], bfr[4];
    #pragma unroll
    for (int mt=0;mt<4;mt++) af[mt] = *(const short8v*)(Ab[mt] + kt*32);
    #pragma unroll
    for (int nt=0;nt<4;nt++) bfr[nt] = *(const short8v*)(Bb[nt] + kt*512);
    #pragma unroll
    for (int mt=0;mt<4;mt++)
      #pragma unroll
      for (int nt=0;nt<4;nt++)
        acc[mt][nt] = __builtin_amdgcn_mfma_f32_16x16x32_bf16(af[mt], bfr[nt], acc[mt][nt], 0,0,0);
  }
  float* C = Cp + blockIdx.z * 819200;
  #pragma unroll
  for (int mt=0;mt<4;mt++)
    #pragma unroll
    for (int nt=0;nt<4;nt++)
      #pragma unroll
      for (int e=0;e<4;e++){
        int row = b0 + (rw<<6) + (mt<<4) + (q<<2) + e;
        int col = n0 + (cw<<6) + (nt<<4) + l16;
        C[row*3200 + col] = acc[mt][nt][e];
      }
}

// reduce 8 partials -> Mh f16, rows padded [i][o][56] (16B-aligned rows)
__global__ __launch_bounds__(256) void reduceM_k(const float* __restrict__ Cp, __half* __restrict__ Mh){
  int idx = blockIdx.x*256 + threadIdx.x;
  if (idx >= 917504) return;            // 256 * 3584
  int i = idx / 3584, r = idx - i*3584;
  int o = r / 56, k = r - o*56;
  float v = 0.f;
  if (k < 50){
    int src = i*3200 + o*50 + k;
    #pragma unroll
    for (int s = 0; s < 8; s++) v += Cp[s*819200 + src];
  }
  Mh[idx] = __float2half(v);
}

// ---- pair v2: grid (64 jb, 8 ib) x 256. Thread (jj=t>>6, o=t&63) owns (j=jb*4+jj, o).
// Mj row segment (7 uint4) register-resident; Mi rows streamed with explicit double buffer.
// Partials (no atomics) -> obp[ib][j*64+o]; finalizeOB_k sums and applies -1 + bf16.
__global__ __launch_bounds__(256) void pairv2_k(const __half* __restrict__ Mh,
                                                float* __restrict__ obp){
  const int t = threadIdx.x, jb = blockIdx.x, ib = blockIdx.y;
  const int o = t & 63, jj = t >> 6;
  const int j = jb*4 + jj;
  const uint4* M4 = (const uint4*)Mh;          // row stride 448 uint4, o-offset o*7
  uint4 mj[7];
  #pragma unroll
  for (int u=0;u<7;u++) mj[u] = M4[j*448 + o*7 + u];
  const int i0 = ib*32;
  uint4 cur[7], nxt[7];
  #pragma unroll
  for (int u=0;u<7;u++) cur[u] = M4[i0*448 + o*7 + u];
  float sum = 0.f;
  for (int ii=0; ii<32; ii++){
    if (ii < 31){
      #pragma unroll
      for (int u=0;u<7;u++) nxt[u] = M4[(i0+ii+1)*448 + o*7 + u];
    }
    __half2 a0 = __float2half2_rn(0.f), a1 = a0, a2 = a0, a3 = a0;
    #pragma unroll
    for (int u=0;u<7;u++){
      const __half2* ah = (const __half2*)&cur[u];
      const __half2* bh = (const __half2*)&mj[u];
      a0 = __hadd2(a0, __habs2(__hsub2(ah[0], bh[0])));
      a1 = __hadd2(a1, __habs2(__hsub2(ah[1], bh[1])));
      a2 = __hadd2(a2, __habs2(__hsub2(ah[2], bh[2])));
      a3 = __hadd2(a3, __habs2(__hsub2(ah[3], bh[3])));
    }
    __half2 s01 = __hadd2(a0, a1), s23 = __hadd2(a2, a3);
    __half2 s = __hadd2(s01, s23);
    float dsum = __low2float(s) + __high2float(s);
    sum += __expf(-dsum);
    #pragma unroll
    for (int u=0;u<7;u++) cur[u] = nxt[u];
  }
  obp[ib*16384 + jb*256 + t] = sum;
}

__global__ __launch_bounds__(256) void finalizeOB_k(const float* __restrict__ obp,
                                                    unsigned short* __restrict__ obb){
  int idx = blockIdx.x*256 + threadIdx.x;    // 16384
  float v = -1.0f;
  #pragma unroll
  for (int s=0;s<8;s++) v += obp[s*16384 + idx];
  obb[idx] = cvt_bf16(v);
}

// ---- gemmFC MFMA, LDS-less: yp[z] = mb(256x4160 bf16) @ Wp(packed bf16)^T, ksplit 13x320.
__global__ __launch_bounds__(256) void gemmFC_k(const unsigned short* __restrict__ featb,
                                                const unsigned short* __restrict__ obb,
                                                const unsigned short* __restrict__ Wp,
                                                float* __restrict__ Cp){
  const int t = threadIdx.x;
  const int o0 = blockIdx.x<<7, b0 = blockIdx.y<<7, kz = blockIdx.z;   // k0 = kz*320
  const int w = t>>6, lane = t&63, q = lane>>4, l16 = lane&15;
  const int rw = w&1, cw = w>>1;
  floatx4 acc[4][4];
  #pragma unroll
  for (int mt=0;mt<4;mt++)
    #pragma unroll
    for (int nt=0;nt<4;nt++) acc[mt][nt] = (floatx4){0.f,0.f,0.f,0.f};
  int rowb[4];
  #pragma unroll
  for (int mt=0;mt<4;mt++) rowb[mt] = b0 + (rw<<6) + (mt<<4) + l16;
  const unsigned short* Bb[4];
  #pragma unroll
  for (int nt=0;nt<4;nt++)
    Bb[nt] = Wp + ((((o0>>4) + (cw<<2) + nt)*130 + kz*10)*64 + lane)*8;
  #pragma unroll 2
  for (int kt=0; kt<10; kt++){
    int k = kz*320 + kt*32 + (q<<3);
    short8v af[4], bfr[4];
    #pragma unroll
    for (int mt=0;mt<4;mt++)
      af[mt] = (k < 4096) ? *(const short8v*)&featb[rowb[mt]*4096 + k]
                          : *(const short8v*)&obb[rowb[mt]*64 + (k-4096)];
    #pragma unroll
    for (int nt=0;nt<4;nt++) bfr[nt] = *(const short8v*)(Bb[nt] + kt*512);
    #pragma unroll
    for (int mt=0;mt<4;mt++)
      #pragma unroll
      for (int nt=0;nt<4;nt++)
        acc[mt][nt] = __builtin_amdgcn_mfma_f32_16x16x32_bf16(af[mt], bfr[nt], acc[mt][nt], 0,0,0);
  }
  float* C = Cp + blockIdx.z * 256000;
  #pragma unroll
  for (int mt=0;mt<4;mt++)
    #pragma unroll
    for (int nt=0;nt<4;nt++)
      #pragma unroll
      for (int e=0;e<4;e++){
        int row = b0 + (rw<<6) + (mt<<4) + (q<<2) + e;
        int col = o0 + (cw<<6) + (nt<<4) + l16;
        if (col < 1000) C[row*1000 + col] = acc[mt][nt][e];
      }
}

__global__ __launch_bounds__(256) void reduceY_k(const float* __restrict__ Cp, const float* __restrict__ bias,
                                                 float* __restrict__ y){
  int idx = blockIdx.x * 256 + threadIdx.x;
  if (idx >= 256000) return;
  int o = idx % 1000;
  float r = bias[o];
  #pragma unroll
  for (int s = 0; s < 13; s++) r += Cp[s*256000 + idx];
  y[idx] = r;
}

extern "C" void kernel_launch(void* const* d_in, const int* in_sizes, int n_in,
                              void* d_out, int out_size, void* d_ws, size_t ws_size,
                              hipStream_t stream){
  const float* x   = (const float*)d_in[0];
  const float* w1  = (const float*)d_in[1];
  const float* g1  = (const float*)d_in[3];
  const float* be1 = (const float*)d_in[4];
  const float* w2  = (const float*)d_in[5];
  const float* g2  = (const float*)d_in[7];
  const float* be2 = (const float*)d_in[8];
  const float* w3  = (const float*)d_in[9];
  const float* g3  = (const float*)d_in[11];
  const float* be3 = (const float*)d_in[12];
  const float* w4  = (const float*)d_in[13];
  const float* g4  = (const float*)d_in[15];
  const float* be4 = (const float*)d_in[16];
  const float* T   = (const float*)d_in[17];
  const float* fcw = (const float*)d_in[18];
  const float* fcb = (const float*)d_in[19];
  float* out = (float*)d_out;
  float* ws  = (float*)d_ws;

  // workspace (float units)
  unsigned short* f1raw = (unsigned short*)ws;               // 8,388,608 fl
  // Tp aliases dead f1raw after conv2: 13,107,200 shorts = 6,553,600 fl <= 8,388,608 ✓
  unsigned short* Tp    = (unsigned short*)ws;
  unsigned short* f2    = (unsigned short*)(ws + 8388608);   // 4,194,304 fl
  unsigned short* f3    = (unsigned short*)(ws + 12582912);  // 2,097,152 fl
  unsigned short* featb = (unsigned short*)(ws + 14680064);  //   524,288 fl
  unsigned short* wb1   = (unsigned short*)(ws + 15204352);  //     4,096 fl
  unsigned short* wb2   = (unsigned short*)(ws + 15208448);  //   102,400 fl
  unsigned short* wb3   = (unsigned short*)(ws + 15310848);  //   409,600 fl
  unsigned short* wb4   = (unsigned short*)(ws + 15720448);  //   294,912 fl
  float* S1    = ws + 16015360;                              //    16,384
  float* Q1    = ws + 16031744;                              //    16,384
  float* S2    = ws + 16048128;                              //    32,768
  float* Q2    = ws + 16080896;                              //    32,768  (end 16,113,664)
  float* Mp    = ws + 16113664;                              // 6,553,600
  // Wp aliases Mp (dead after reduceM): 4,259,840 shorts = 2,129,920 fl <= 6,553,600 ✓
  unsigned short* Wp  = (unsigned short*)(ws + 16113664);
  __half* Mh   = (__half*)(ws + 22667264);                   //   458,752 fl (256x3584 halfs, rows padded to 56)
  unsigned short* obb = (unsigned short*)(ws + 23142400);    //     8,192 fl
  float* yp    = ws + 23150592;                              // 3,328,000 (end 26,478,592 fl)
  float* obp   = ws + 26478592;                              //   131,072 (8 x 16384, end 26,609,664 fl)
  float* feat  = out;
  float* y     = out + 1048576;

  prep_k<<<dim3(6720), 256, 0, stream>>>(w1, w2, w3, w4, wb1, wb2, wb3, wb4, S1);

  conv1_k<<<dim3(512),     256, 0, stream>>>(x, wb1, S1, Q1, f1raw);
  conv2_k<<<dim3(512),     512, 0, stream>>>(f1raw, wb2, S1, Q1, g1, be1, S2, Q2, f2);
  packT_k<<<dim3(3200),    256, 0, stream>>>(T, Tp);
  conv3_k<<<dim3(256, 2),  512, 0, stream>>>(f2, wb3, S2, Q2, g2, be2, g3, be3, f3);
  conv4_k<<<dim3(128, 4),  256, 0, stream>>>(f3, wb4, g4, be4, feat, featb);

  gemmM_k  <<<dim3(25, 2, 8),  256, 0, stream>>>(featb, Tp, Mp);
  reduceM_k<<<dim3(3584),      256, 0, stream>>>(Mp, Mh);
  packW_k  <<<dim3(2080),      256, 0, stream>>>(fcw, Wp);
  pairv2_k <<<dim3(64, 8),     256, 0, stream>>>(Mh, obp);
  finalizeOB_k<<<dim3(64),     256, 0, stream>>>(obp, obb);
  gemmFC_k <<<dim3(8, 2, 13),  256, 0, stream>>>(featb, obb, Wp, yp);
  reduceY_k<<<dim3(1000),      256, 0, stream>>>(yp, fcb, y);
}

// Round 9
// 329.778 us; speedup vs baseline: 1.1953x; 1.0742x over previous
//
#include <hip/hip_runtime.h>
#include <hip/hip_fp16.h>
#include <math.h>

#define EPSF 1e-5f

typedef __attribute__((ext_vector_type(4))) float  floatx4;
typedef __attribute__((ext_vector_type(4))) short  short4v;
typedef __attribute__((ext_vector_type(8))) short  short8v;

__device__ __forceinline__ unsigned short cvt_bf16(float f){
  unsigned u = __float_as_uint(f);
  unsigned r = (u + 0x7FFFu + ((u >> 16) & 1u)) >> 16;
  return (unsigned short)r;
}
__device__ __forceinline__ float bf2f(unsigned short h){
  return __uint_as_float(((unsigned)h) << 16);
}
__device__ __forceinline__ short8v ld_frag(const unsigned short* p){
  short4v lo = *(const short4v*)p;
  short4v hi = *(const short4v*)(p + 4);
  return __builtin_shufflevector(lo, hi, 0,1,2,3,4,5,6,7);
}
__device__ __forceinline__ float lrelu(float x){ return x >= 0.f ? x : 0.2f*x; }

// ---- merged prep. Weights fragment-packed: [co16grp][tap][ccgrp][lane64][8]
// b-frag lane mapping (16x16x32): co_local = lane&15, k = (lane>>4)*8 + j.
__global__ __launch_bounds__(256) void prep_k(const float* __restrict__ w1, const float* __restrict__ w2,
                                              const float* __restrict__ w3, const float* __restrict__ w4,
                                              unsigned short* __restrict__ wb1, unsigned short* __restrict__ wb2,
                                              unsigned short* __restrict__ wb3, unsigned short* __restrict__ wb4,
                                              float* __restrict__ SQ){
  int b = blockIdx.x, t = threadIdx.x;
  if (b < 32){                       // conv1: 4 grp x 4 ks x 512; k=(kh*6+kw)*4+ci over K=128
    int idx = b*256 + t;             // 8192 shorts
    int j = idx&7, lane = (idx>>3)&63, ks = (idx>>9)&3, grp = idx>>11;
    int co = grp*16 + (lane&15);
    int k = ks*32 + ((lane>>4)<<3) + j;
    int tap6 = k>>2, ci = k&3;
    int kh = tap6/6, kw = tap6 - kh*6;
    float v = 0.f;
    if (ci < 3 && kh < 5 && kw < 5) v = w1[(co*3 + ci)*25 + kh*5 + kw];
    wb1[idx] = cvt_bf16(v);
  } else if (b < 832){               // conv2: 8 grp x 25 tap x 2 ccg x 512 = 204800
    int idx = (b-32)*256 + t;
    int grp = idx/25600, rem = idx - grp*25600;
    int tap = rem/1024, rem2 = rem - tap*1024;
    int ccg = rem2>>9, lane = (rem2>>3)&63, j = rem2&7;
    int co = grp*16 + (lane&15);
    int ci = ccg*32 + ((lane>>4)<<3) + j;
    wb2[idx] = cvt_bf16(w2[(co*64 + ci)*25 + tap]);
  } else if (b < 4032){              // conv3: 16 grp x 25 tap x 4 ccg x 512 = 819200
    int idx = (b-832)*256 + t;
    int grp = idx/51200, rem = idx - grp*51200;
    int tap = rem/2048, rem2 = rem - tap*2048;
    int ccg = rem2>>9, lane = (rem2>>3)&63, j = rem2&7;
    int co = grp*16 + (lane&15);
    int ci = ccg*32 + ((lane>>4)<<3) + j;
    wb3[idx] = cvt_bf16(w3[(co*128 + ci)*25 + tap]);
  } else if (b < 6336){              // conv4: 16 grp x 9 tap x 8 ccg x 512 = 589824
    int idx = (b-4032)*256 + t;
    int grp = idx/36864, rem = idx - grp*36864;
    int tap = rem/4096, rem2 = rem - tap*4096;
    int ccg = rem2>>9, lane = (rem2>>3)&63, j = rem2&7;
    int co = grp*16 + (lane&15);
    int ci = ccg*32 + ((lane>>4)<<3) + j;
    wb4[idx] = cvt_bf16(w4[(co*256 + ci)*9 + tap]);
  } else {                           // zero S1/Q1/S2/Q2 (98304 floats)
    int idx = (b-6336)*256 + t;
    SQ[idx] = 0.f;
  }
}

// ---- packT_k: T (4096x3200 fp32) -> bf16 MFMA b-fragment layout.
// Tp: [ngrp(200)][ktile(128)][lane(64)][8]; aliases dead f1raw (launched after conv2).
__global__ __launch_bounds__(256) void packT_k(const float* __restrict__ T,
                                               unsigned short* __restrict__ Tp){
  const int b = blockIdx.x, t = threadIdx.x;
  __shared__ float tile[32][133];
  const int nb = b % 25, kt = b / 25;
  const int n0 = nb*128, k0 = kt*32;
  #pragma unroll
  for (int m=0;m<4;m++){
    int idx = m*256 + t;
    int row = idx>>5, c4 = (idx&31)<<2;
    const float4 v = *(const float4*)&T[(k0+row)*3200 + n0 + c4];
    tile[row][c4]   = v.x; tile[row][c4+1] = v.y;
    tile[row][c4+2] = v.z; tile[row][c4+3] = v.w;
  }
  __syncthreads();
  #pragma unroll
  for (int m=0;m<2;m++){
    int c = m*256 + t;
    int ngl = c>>6, lane = c&63, q = lane>>4, r = lane&15;
    unsigned short h[8];
    #pragma unroll
    for (int j=0;j<8;j++) h[j] = cvt_bf16(tile[q*8+j][ngl*16 + r]);
    *(uint4*)&Tp[(((nb*8 + ngl)*128 + kt)*64 + lane)*8] = *(const uint4*)h;
  }
}

// ---- packW_k: fcw (1000x4160 fp32) -> bf16 b-fragment layout. Aliases Mp (after reduceM).
__global__ __launch_bounds__(256) void packW_k(const float* __restrict__ W,
                                               unsigned short* __restrict__ Wp){
  int idx = blockIdx.x*256 + threadIdx.x;   // 532480 chunks of 8
  int lane = idx & 63, rem = idx >> 6;
  int kt = rem % 130, ng = rem / 130;
  int q = lane>>4, r = lane&15;
  int orow = ng*16 + r, k = kt*32 + (q<<3);
  unsigned short h[8] = {0,0,0,0,0,0,0,0};
  if (orow < 1000){
    float4 v0 = *(const float4*)&W[orow*4160 + k];
    float4 v1 = *(const float4*)&W[orow*4160 + k + 4];
    h[0]=cvt_bf16(v0.x); h[1]=cvt_bf16(v0.y); h[2]=cvt_bf16(v0.z); h[3]=cvt_bf16(v0.w);
    h[4]=cvt_bf16(v1.x); h[5]=cvt_bf16(v1.y); h[6]=cvt_bf16(v1.z); h[7]=cvt_bf16(v1.w);
  }
  *(uint4*)&Wp[idx*8] = *(const uint4*)h;
}

// ---- conv1: half-image blocks (grid 512). Raw f1 + S1/Q1 atomics.
// img has 36 rows: row 35 is an always-zero guard row (kh=5 pad taps land there).
__global__ __launch_bounds__(256) void conv1_k(const float* __restrict__ x, const unsigned short* __restrict__ wb1P,
                                               float* __restrict__ S1, float* __restrict__ Q1,
                                               unsigned short* __restrict__ f1raw){
  const int t = threadIdx.x, n = blockIdx.x>>1, half = blockIdx.x&1;
  const int w = t>>6, lane = t&63, q = lane>>4, l16 = lane&15;
  __shared__ __align__(16) unsigned short img[36*68*4];   // [tih][iw+2][ci] 19.6 KB
  short8v bf[4][4];
  #pragma unroll
  for (int nt=0;nt<4;nt++)
    #pragma unroll
    for (int ks=0;ks<4;ks++)
      bf[nt][ks] = *(const short8v*)&wb1P[((nt*4+ks)*64 + lane)*8];
  for (int i=t; i<4896; i+=256) ((unsigned*)img)[i] = 0u;
  __syncthreads();
  for (int idx=t; idx<1680; idx+=256){
    int ci = idx/560, rem = idx - ci*560;
    int tih = rem>>4, iw4 = (rem&15)<<2;
    int ih = half*32 - 2 + tih;
    if ((unsigned)ih < 64u){
      float4 v = *(const float4*)&x[((n*3+ci)<<12) + (ih<<6) + iw4];
      int base = (tih*68 + iw4 + 2)*4 + ci;
      img[base]    = cvt_bf16(v.x);
      img[base+4]  = cvt_bf16(v.y);
      img[base+8]  = cvt_bf16(v.z);
      img[base+12] = cvt_bf16(v.w);
    }
  }
  __syncthreads();
  floatx4 acc[8][4];
  #pragma unroll
  for (int mi=0;mi<8;mi++)
    #pragma unroll
    for (int nt=0;nt<4;nt++) acc[mi][nt] = (floatx4){0.f,0.f,0.f,0.f};
  #pragma unroll
  for (int mi=0; mi<8; mi++){
    int r = w*8 + mi;                 // mtile 0..31 within half
    int ohl = r>>1, ow = ((r&1)<<4) + l16;
    #pragma unroll
    for (int ks=0; ks<4; ks++){
      int t0 = ks*8 + 2*q;
      int kh = t0/6, kw = t0 - kh*6;
      short8v a = ld_frag(&img[((ohl*2+kh)*68 + ow*2 + kw)*4]);
      #pragma unroll
      for (int nt=0; nt<4; nt++)
        acc[mi][nt] = __builtin_amdgcn_mfma_f32_16x16x32_bf16(a, bf[nt][ks], acc[mi][nt], 0,0,0);
    }
  }
  float sreg[4] = {0,0,0,0}, qreg[4] = {0,0,0,0};
  #pragma unroll
  for (int mi=0;mi<8;mi++){
    int r = w*8 + mi;
    #pragma unroll
    for (int nt=0;nt<4;nt++)
      #pragma unroll
      for (int e=0;e<4;e++){
        float v = acc[mi][nt][e];
        sreg[nt] += v; qreg[nt] += v*v;
        int px = half*512 + (r<<4) + (q<<2) + e;
        f1raw[(((n<<10)+px)<<6) + (nt<<4) + l16] = cvt_bf16(v);
      }
  }
  #pragma unroll
  for (int nt=0;nt<4;nt++){
    float s = sreg[nt], qq = qreg[nt];
    s  += __shfl_xor(s,16,64);  s  += __shfl_xor(s,32,64);
    qq += __shfl_xor(qq,16,64); qq += __shfl_xor(qq,32,64);
    if (q==0){
      atomicAdd(&S1[(n<<6) + (nt<<4) + l16], s);
      atomicAdd(&Q1[(n<<6) + (nt<<4) + l16], qq);
    }
  }
}

// ---- conv2: Mb=128 x Nb=128, grid 512 x 512thr. 4-deep B ring + 1-tap A double buffer.
// Slot swizzle REVERTED (round-8 post-mortem: 4-way conflict costs ~8%, swizzle VALU cost more).
__global__ __launch_bounds__(512) void conv2_k(const unsigned short* __restrict__ fin,
                                               const unsigned short* __restrict__ wbP,
                                               const float* __restrict__ S1, const float* __restrict__ Q1,
                                               const float* __restrict__ g1, const float* __restrict__ be1,
                                               float* __restrict__ S2, float* __restrict__ Q2,
                                               unsigned short* __restrict__ fout){
  const int t = threadIdx.x;
  const int n = blockIdx.x >> 1, half = blockIdx.x & 1;
  const int w = t>>6, lane = t&63, q = lane>>4, l16 = lane&15;
  const int rw = w&1, cw = w>>1;           // rw 0..1, cw 0..3
  __shared__ __align__(16) unsigned short tile[684*40];   // 19x36 cells, 54.7 KB
  __shared__ float gmA[64], btA[64];
  if (t < 64){
    float S = S1[(n<<6)+t], Q = Q1[(n<<6)+t];
    float mu = S*(1.f/1024.f), var = fmaxf(Q*(1.f/1024.f) - mu*mu, 0.f);
    float r = rsqrtf(var+EPSF)*g1[t];
    gmA[t] = r; btA[t] = be1[t] - mu*r;
  }
  __syncthreads();
  floatx4 acc[4][2];
  #pragma unroll
  for (int mt=0;mt<4;mt++)
    #pragma unroll
    for (int nt=0;nt<2;nt++) acc[mt][nt] = (floatx4){0.f,0.f,0.f,0.f};
  int cellb[4];
  #pragma unroll
  for (int mt=0;mt<4;mt++){
    int r = rw*64 + mt*16 + l16;
    int ohl = r>>4, ow = r&15;
    cellb[mt] = (2*ohl)*36 + 2*ow;
  }
  for (int ccg = 0; ccg < 2; ccg++){
    const int cc = ccg<<5;
    if (ccg) __syncthreads();
    #pragma unroll
    for (int it=0; it<6; it++){
      int idx = it*512 + t;
      if (idx < 2736){
        int cell = idx>>2, ci0 = (idx&3)<<3;
        int tih = cell/36, tiw = cell - tih*36;
        int ih = half*16 + tih - 2, iw = tiw - 2;
        uint4 v = {0u,0u,0u,0u};
        if ((unsigned)ih < 32u && (unsigned)iw < 32u){
          v = *(const uint4*)&fin[(((n*32+ih)*32 + iw)<<6) + cc + ci0];
          unsigned short* hp = (unsigned short*)&v;
          #pragma unroll
          for (int jj=0;jj<8;jj++){
            int c = cc + ci0 + jj;
            hp[jj] = cvt_bf16(lrelu(bf2f(hp[jj])*gmA[c]+btA[c]));
          }
        }
        *(uint4*)&tile[cell*40 + ci0] = v;
      }
    }
    __syncthreads();
    const unsigned short* bp[2];
    #pragma unroll
    for (int nt=0;nt<2;nt++)
      bp[nt] = wbP + ((((cw*2+nt)*25)*2 + ccg)<<9) + lane*8;   // +tap*1024
    short8v bq[2][4];                       // 4-deep static B prefetch ring
    #pragma unroll
    for (int p=0;p<4;p++)
      #pragma unroll
      for (int nt=0;nt<2;nt++) bq[nt][p] = *(const short8v*)(bp[nt] + (p<<10));
    short8v acur[4];                        // 1-tap A double buffer
    #pragma unroll
    for (int mt=0;mt<4;mt++) acur[mt] = *(const short8v*)&tile[cellb[mt]*40 + q*8];
    #pragma unroll
    for (int tap=0; tap<25; tap++){
      short8v anx[4];
      if (tap+1 < 25){
        const int t1 = tap+1, kh1 = t1/5, kw1 = t1 - kh1*5;
        const int aoff1 = kh1*36 + kw1;
        #pragma unroll
        for (int mt=0;mt<4;mt++) anx[mt] = *(const short8v*)&tile[(cellb[mt]+aoff1)*40 + q*8];
      }
      #pragma unroll
      for (int mt=0;mt<4;mt++)
        #pragma unroll
        for (int nt=0;nt<2;nt++)
          acc[mt][nt] = __builtin_amdgcn_mfma_f32_16x16x32_bf16(acur[mt], bq[nt][tap&3], acc[mt][nt], 0,0,0);
      if (tap+4 < 25){
        #pragma unroll
        for (int nt=0;nt<2;nt++) bq[nt][tap&3] = *(const short8v*)(bp[nt] + ((tap+4)<<10));
      }
      if (tap+1 < 25){
        #pragma unroll
        for (int mt=0;mt<4;mt++) acur[mt] = anx[mt];
      }
    }
  }
  #pragma unroll
  for (int nt=0;nt<2;nt++){
    int co = cw*32 + nt*16 + l16;
    float s=0.f, qq=0.f;
    #pragma unroll
    for (int mt=0;mt<4;mt++)
      #pragma unroll
      for (int e=0;e<4;e++){ float xv = acc[mt][nt][e]; s += xv; qq += xv*xv; }
    s  += __shfl_xor(s,16,64);  s  += __shfl_xor(s,32,64);
    qq += __shfl_xor(qq,16,64); qq += __shfl_xor(qq,32,64);
    if (q == 0){
      atomicAdd(&S2[n*128 + co], s);
      atomicAdd(&Q2[n*128 + co], qq);
    }
    #pragma unroll
    for (int mt=0;mt<4;mt++)
      #pragma unroll
      for (int e=0;e<4;e++){
        int px = half*128 + rw*64 + mt*16 + q*4 + e;
        fout[((n<<8) + px)*128 + co] = cvt_bf16(acc[mt][nt][e]);
      }
  }
}

// ---- conv3: Mb=64 x Nb=128, grid (256,2) x 512thr. 4-deep B ring + 1-tap A double buffer.
__global__ __launch_bounds__(512) void conv3_k(const unsigned short* __restrict__ fin,
                                               const unsigned short* __restrict__ wbP,
                                               const float* __restrict__ S2, const float* __restrict__ Q2,
                                               const float* __restrict__ g2, const float* __restrict__ be2,
                                               const float* __restrict__ g, const float* __restrict__ be,
                                               unsigned short* __restrict__ fout){
  const int t = threadIdx.x, n = blockIdx.x, co0 = blockIdx.y<<7;
  const int w = t>>6, lane = t&63, q = lane>>4, l16 = lane&15;
  const int rw = w&1, cw = w>>1;           // rw 0..1, cw 0..3
  __shared__ __align__(16) unsigned short tile[361*40];   // 28.9 KB
  __shared__ float gmA[128], btA[128];
  __shared__ float SQs[2][128], SQq[2][128];
  if (t < 128){
    float S = S2[n*128+t], Q = Q2[n*128+t];
    float mu = S*(1.f/256.f), var = fmaxf(Q*(1.f/256.f) - mu*mu, 0.f);
    float r = rsqrtf(var+EPSF)*g2[t];
    gmA[t] = r; btA[t] = be2[t] - mu*r;
  }
  __syncthreads();
  floatx4 acc[2][2];
  #pragma unroll
  for (int mt=0;mt<2;mt++)
    #pragma unroll
    for (int nt=0;nt<2;nt++) acc[mt][nt] = (floatx4){0.f,0.f,0.f,0.f};
  int cellb[2];
  #pragma unroll
  for (int mt=0;mt<2;mt++){
    int r = rw*32 + mt*16 + l16;
    int oh = r>>3, ow = r&7;
    cellb[mt] = (2*oh)*19 + 2*ow;
  }
  for (int ccg = 0; ccg < 4; ccg++){
    const int cc = ccg<<5;
    if (ccg) __syncthreads();
    #pragma unroll
    for (int it=0; it<3; it++){
      int idx = it*512 + t;
      if (idx < 1444){
        int cell = idx>>2, ci0 = (idx&3)<<3;
        int tih = cell/19, tiw = cell - tih*19;
        int ih = tih - 2, iw = tiw - 2;
        uint4 v = {0u,0u,0u,0u};
        if ((unsigned)ih < 16u && (unsigned)iw < 16u){
          v = *(const uint4*)&fin[(((n*16+ih)*16 + iw)<<7) + cc + ci0];
          unsigned short* hp = (unsigned short*)&v;
          #pragma unroll
          for (int jj=0;jj<8;jj++){
            int c = cc + ci0 + jj;
            hp[jj] = cvt_bf16(lrelu(bf2f(hp[jj])*gmA[c]+btA[c]));
          }
        }
        *(uint4*)&tile[cell*40 + ci0] = v;
      }
    }
    __syncthreads();
    const unsigned short* bp[2];
    #pragma unroll
    for (int nt=0;nt<2;nt++)
      bp[nt] = wbP + (((((co0>>4)+cw*2+nt)*25)*4 + ccg)<<9) + lane*8;  // +tap*2048
    short8v bq[2][4];                       // 4-deep static B prefetch ring
    #pragma unroll
    for (int p=0;p<4;p++)
      #pragma unroll
      for (int nt=0;nt<2;nt++) bq[nt][p] = *(const short8v*)(bp[nt] + (p<<11));
    short8v acur[2];                        // 1-tap A double buffer
    #pragma unroll
    for (int mt=0;mt<2;mt++) acur[mt] = *(const short8v*)&tile[cellb[mt]*40 + q*8];
    #pragma unroll
    for (int tap=0; tap<25; tap++){
      short8v anx[2];
      if (tap+1 < 25){
        const int t1 = tap+1, kh1 = t1/5, kw1 = t1 - kh1*5;
        const int aoff1 = kh1*19 + kw1;
        #pragma unroll
        for (int mt=0;mt<2;mt++) anx[mt] = *(const short8v*)&tile[(cellb[mt]+aoff1)*40 + q*8];
      }
      #pragma unroll
      for (int mt=0;mt<2;mt++)
        #pragma unroll
        for (int nt=0;nt<2;nt++)
          acc[mt][nt] = __builtin_amdgcn_mfma_f32_16x16x32_bf16(acur[mt], bq[nt][tap&3], acc[mt][nt], 0,0,0);
      if (tap+4 < 25){
        #pragma unroll
        for (int nt=0;nt<2;nt++) bq[nt][tap&3] = *(const short8v*)(bp[nt] + ((tap+4)<<11));
      }
      if (tap+1 < 25){
        #pragma unroll
        for (int mt=0;mt<2;mt++) acur[mt] = anx[mt];
      }
    }
  }
  #pragma unroll
  for (int nt=0;nt<2;nt++){
    int lcol = cw*32 + nt*16 + l16;
    float s=0.f, qq=0.f;
    #pragma unroll
    for (int mt=0;mt<2;mt++)
      #pragma unroll
      for (int e=0;e<4;e++){ float xv = acc[mt][nt][e]; s += xv; qq += xv*xv; }
    s  += __shfl_xor(s,16,64);  s  += __shfl_xor(s,32,64);
    qq += __shfl_xor(qq,16,64); qq += __shfl_xor(qq,32,64);
    if (q == 0){ SQs[rw][lcol] = s; SQq[rw][lcol] = qq; }
  }
  __syncthreads();
  #pragma unroll
  for (int nt=0;nt<2;nt++){
    int lcol = cw*32 + nt*16 + l16, co = co0 + lcol;
    float S = SQs[0][lcol] + SQs[1][lcol];
    float Q = SQq[0][lcol] + SQq[1][lcol];
    float mu = S*(1.f/64.f), var = fmaxf(Q*(1.f/64.f) - mu*mu, 0.f);
    float gmv = rsqrtf(var+EPSF)*g[co];
    float btv = be[co] - mu*gmv;
    #pragma unroll
    for (int mt=0;mt<2;mt++)
      #pragma unroll
      for (int e=0;e<4;e++){
        int row = rw*32 + mt*16 + q*4 + e;
        fout[((n<<6) + row)*256 + co] = cvt_bf16(lrelu(acc[mt][nt][e]*gmv+btv));
      }
  }
}

// ---- conv4: Mb=32 (2 images) x Nb=64, grid (128,4). 4-deep B ring. Fused IN4+lrelu.
__global__ __launch_bounds__(256) void conv4_k(const unsigned short* __restrict__ fin,
                                               const unsigned short* __restrict__ wbP,
                                               const float* __restrict__ g, const float* __restrict__ be,
                                               float* __restrict__ feat, unsigned short* __restrict__ featb){
  const int t = threadIdx.x;
  const int n0 = blockIdx.x << 1, co0 = blockIdx.y << 6;
  const int w = t>>6, lane = t&63, q = lane>>4, l16 = lane&15;
  const int rw = w&1, cw = w>>1;
  __shared__ __align__(16) unsigned short tile[2*81*40];
  floatx4 acc[2];
  acc[0] = (floatx4){0.f,0.f,0.f,0.f};
  acc[1] = (floatx4){0.f,0.f,0.f,0.f};
  const int oh = l16>>2, ow = l16&3;
  const int cellb = (2*oh)*9 + 2*ow;
  for (int ccg = 0; ccg < 8; ccg++){
    const int cc = ccg<<5;
    if (ccg) __syncthreads();
    #pragma unroll
    for (int it=0; it<3; it++){
      int idx = it*256 + t;
      if (idx < 648){
        int img = idx >= 324 ? 1 : 0;
        int rem = idx - img*324;
        int cell = rem>>2, ci0 = (rem&3)<<3;
        int tih = cell/9, tiw = cell - tih*9;
        int ih = tih - 1, iw = tiw - 1;
        uint4 v = {0u,0u,0u,0u};
        if ((unsigned)ih < 8u && (unsigned)iw < 8u)
          v = *(const uint4*)&fin[((((n0+img)*8+ih)*8 + iw)<<8) + cc + ci0];
        *(uint4*)&tile[(img*81+cell)*40 + ci0] = v;
      }
    }
    __syncthreads();
    const unsigned short* bp[2];
    #pragma unroll
    for (int nt=0;nt<2;nt++)
      bp[nt] = wbP + (((((co0>>4)+cw*2+nt)*9)*8 + ccg)<<9) + lane*8;  // +tap*4096
    short8v bq[2][4];
    #pragma unroll
    for (int p=0;p<4;p++)
      #pragma unroll
      for (int nt=0;nt<2;nt++) bq[nt][p] = *(const short8v*)(bp[nt] + (p<<12));
    #pragma unroll
    for (int tap=0; tap<9; tap++){
      const int kh = tap/3, kw = tap - kh*3;
      short8v a = *(const short8v*)&tile[(rw*81 + cellb + kh*9 + kw)*40 + q*8];
      #pragma unroll
      for (int nt=0;nt<2;nt++)
        acc[nt] = __builtin_amdgcn_mfma_f32_16x16x32_bf16(a, bq[nt][tap&3], acc[nt], 0,0,0);
      if (tap+4 < 9){
        #pragma unroll
        for (int nt=0;nt<2;nt++) bq[nt][tap&3] = *(const short8v*)(bp[nt] + ((tap+4)<<12));
      }
    }
  }
  const int nn = n0 + rw;
  #pragma unroll
  for (int nt=0;nt<2;nt++){
    int co = co0 + cw*32 + nt*16 + l16;
    float s=0.f, qq=0.f;
    #pragma unroll
    for (int e=0;e<4;e++){ float xv = acc[nt][e]; s += xv; qq += xv*xv; }
    s  += __shfl_xor(s,16,64);  s  += __shfl_xor(s,32,64);
    qq += __shfl_xor(qq,16,64); qq += __shfl_xor(qq,32,64);
    float mu = s*(1.f/16.f), var = fmaxf(qq*(1.f/16.f) - mu*mu, 0.f);
    float gmv = rsqrtf(var+EPSF)*g[co];
    float btv = be[co] - mu*gmv;
    #pragma unroll
    for (int e=0;e<4;e++){
      int px = q*4 + e;
      float vv = lrelu(acc[nt][e]*gmv+btv);
      feat [(nn<<12) + (co<<4) + px] = vv;
      featb[(nn<<12) + (co<<4) + px] = cvt_bf16(vv);
    }
  }
}

// ---- gemmM MFMA, LDS-less: Cp[z] = featb(256x4096 bf16) @ Tp(packed bf16), ksplit 8x512.
__global__ __launch_bounds__(256) void gemmM_k(const unsigned short* __restrict__ A,
                                               const unsigned short* __restrict__ Tp,
                                               float* __restrict__ Cp){
  const int t = threadIdx.x;
  const int n0 = blockIdx.x<<7, b0 = blockIdx.y<<7, k0 = blockIdx.z<<9;
  const int w = t>>6, lane = t&63, q = lane>>4, l16 = lane&15;
  const int rw = w&1, cw = w>>1;
  floatx4 acc[4][4];
  #pragma unroll
  for (int mt=0;mt<4;mt++)
    #pragma unroll
    for (int nt=0;nt<4;nt++) acc[mt][nt] = (floatx4){0.f,0.f,0.f,0.f};
  const unsigned short* Ab[4];
  const unsigned short* Bb[4];
  #pragma unroll
  for (int mt=0;mt<4;mt++)
    Ab[mt] = A + (b0 + (rw<<6) + (mt<<4) + l16)*4096 + k0 + (q<<3);
  #pragma unroll
  for (int nt=0;nt<4;nt++)
    Bb[nt] = Tp + ((((n0>>4) + (cw<<2) + nt)*128 + (k0>>5))*64 + lane)*8;
  #pragma unroll 4
  for (int kt=0; kt<16; kt++){
    short8v af[4], bfr[4];
    #pragma unroll
    for (int mt=0;mt<4;mt++) af[mt] = *(const short8v*)(Ab[mt] + kt*32);
    #pragma unroll
    for (int nt=0;nt<4;nt++) bfr[nt] = *(const short8v*)(Bb[nt] + kt*512);
    #pragma unroll
    for (int mt=0;mt<4;mt++)
      #pragma unroll
      for (int nt=0;nt<4;nt++)
        acc[mt][nt] = __builtin_amdgcn_mfma_f32_16x16x32_bf16(af[mt], bfr[nt], acc[mt][nt], 0,0,0);
  }
  float* C = Cp + blockIdx.z * 819200;
  #pragma unroll
  for (int mt=0;mt<4;mt++)
    #pragma unroll
    for (int nt=0;nt<4;nt++)
      #pragma unroll
      for (int e=0;e<4;e++){
        int row = b0 + (rw<<6) + (mt<<4) + (q<<2) + e;
        int col = n0 + (cw<<6) + (nt<<4) + l16;
        C[row*3200 + col] = acc[mt][nt][e];
      }
}

// reduce 8 partials -> Mh f16, rows padded [i][o][56] (16B-aligned rows)
__global__ __launch_bounds__(256) void reduceM_k(const float* __restrict__ Cp, __half* __restrict__ Mh){
  int idx = blockIdx.x*256 + threadIdx.x;
  if (idx >= 917504) return;            // 256 * 3584
  int i = idx / 3584, r = idx - i*3584;
  int o = r / 56, k = r - o*56;
  float v = 0.f;
  if (k < 50){
    int src = i*3200 + o*50 + k;
    #pragma unroll
    for (int s = 0; s < 8; s++) v += Cp[s*819200 + src];
  }
  Mh[idx] = __float2half(v);
}

// ---- pair v2: grid (64 jb, 8 ib) x 256. Thread (jj=t>>6, o=t&63) owns (j=jb*4+jj, o).
// Mj row segment (7 uint4) register-resident; Mi rows streamed with explicit double buffer.
__global__ __launch_bounds__(256) void pairv2_k(const __half* __restrict__ Mh,
                                                float* __restrict__ obp){
  const int t = threadIdx.x, jb = blockIdx.x, ib = blockIdx.y;
  const int o = t & 63, jj = t >> 6;
  const int j = jb*4 + jj;
  const uint4* M4 = (const uint4*)Mh;          // row stride 448 uint4, o-offset o*7
  uint4 mj[7];
  #pragma unroll
  for (int u=0;u<7;u++) mj[u] = M4[j*448 + o*7 + u];
  const int i0 = ib*32;
  uint4 cur[7], nxt[7];
  #pragma unroll
  for (int u=0;u<7;u++) cur[u] = M4[i0*448 + o*7 + u];
  float sum = 0.f;
  for (int ii=0; ii<32; ii++){
    if (ii < 31){
      #pragma unroll
      for (int u=0;u<7;u++) nxt[u] = M4[(i0+ii+1)*448 + o*7 + u];
    }
    __half2 a0 = __float2half2_rn(0.f), a1 = a0, a2 = a0, a3 = a0;
    #pragma unroll
    for (int u=0;u<7;u++){
      const __half2* ah = (const __half2*)&cur[u];
      const __half2* bh = (const __half2*)&mj[u];
      a0 = __hadd2(a0, __habs2(__hsub2(ah[0], bh[0])));
      a1 = __hadd2(a1, __habs2(__hsub2(ah[1], bh[1])));
      a2 = __hadd2(a2, __habs2(__hsub2(ah[2], bh[2])));
      a3 = __hadd2(a3, __habs2(__hsub2(ah[3], bh[3])));
    }
    __half2 s01 = __hadd2(a0, a1), s23 = __hadd2(a2, a3);
    __half2 s = __hadd2(s01, s23);
    float dsum = __low2float(s) + __high2float(s);
    sum += __expf(-dsum);
    #pragma unroll
    for (int u=0;u<7;u++) cur[u] = nxt[u];
  }
  obp[ib*16384 + jb*256 + t] = sum;
}

__global__ __launch_bounds__(256) void finalizeOB_k(const float* __restrict__ obp,
                                                    unsigned short* __restrict__ obb){
  int idx = blockIdx.x*256 + threadIdx.x;    // 16384
  float v = -1.0f;
  #pragma unroll
  for (int s=0;s<8;s++) v += obp[s*16384 + idx];
  obb[idx] = cvt_bf16(v);
}

// ---- gemmFC MFMA, LDS-less: yp[z] = mb(256x4160 bf16) @ Wp(packed bf16)^T, ksplit 13x320.
__global__ __launch_bounds__(256) void gemmFC_k(const unsigned short* __restrict__ featb,
                                                const unsigned short* __restrict__ obb,
                                                const unsigned short* __restrict__ Wp,
                                                float* __restrict__ Cp){
  const int t = threadIdx.x;
  const int o0 = blockIdx.x<<7, b0 = blockIdx.y<<7, kz = blockIdx.z;   // k0 = kz*320
  const int w = t>>6, lane = t&63, q = lane>>4, l16 = lane&15;
  const int rw = w&1, cw = w>>1;
  floatx4 acc[4][4];
  #pragma unroll
  for (int mt=0;mt<4;mt++)
    #pragma unroll
    for (int nt=0;nt<4;nt++) acc[mt][nt] = (floatx4){0.f,0.f,0.f,0.f};
  int rowb[4];
  #pragma unroll
  for (int mt=0;mt<4;mt++) rowb[mt] = b0 + (rw<<6) + (mt<<4) + l16;
  const unsigned short* Bb[4];
  #pragma unroll
  for (int nt=0;nt<4;nt++)
    Bb[nt] = Wp + ((((o0>>4) + (cw<<2) + nt)*130 + kz*10)*64 + lane)*8;
  #pragma unroll 2
  for (int kt=0; kt<10; kt++){
    int k = kz*320 + kt*32 + (q<<3);
    short8v af[4], bfr[4];
    #pragma unroll
    for (int mt=0;mt<4;mt++)
      af[mt] = (k < 4096) ? *(const short8v*)&featb[rowb[mt]*4096 + k]
                          : *(const short8v*)&obb[rowb[mt]*64 + (k-4096)];
    #pragma unroll
    for (int nt=0;nt<4;nt++) bfr[nt] = *(const short8v*)(Bb[nt] + kt*512);
    #pragma unroll
    for (int mt=0;mt<4;mt++)
      #pragma unroll
      for (int nt=0;nt<4;nt++)
        acc[mt][nt] = __builtin_amdgcn_mfma_f32_16x16x32_bf16(af[mt], bfr[nt], acc[mt][nt], 0,0,0);
  }
  float* C = Cp + blockIdx.z * 256000;
  #pragma unroll
  for (int mt=0;mt<4;mt++)
    #pragma unroll
    for (int nt=0;nt<4;nt++)
      #pragma unroll
      for (int e=0;e<4;e++){
        int row = b0 + (rw<<6) + (mt<<4) + (q<<2) + e;
        int col = o0 + (cw<<6) + (nt<<4) + l16;
        if (col < 1000) C[row*1000 + col] = acc[mt][nt][e];
      }
}

__global__ __launch_bounds__(256) void reduceY_k(const float* __restrict__ Cp, const float* __restrict__ bias,
                                                 float* __restrict__ y){
  int idx = blockIdx.x * 256 + threadIdx.x;
  if (idx >= 256000) return;
  int o = idx % 1000;
  float r = bias[o];
  #pragma unroll
  for (int s = 0; s < 13; s++) r += Cp[s*256000 + idx];
  y[idx] = r;
}

extern "C" void kernel_launch(void* const* d_in, const int* in_sizes, int n_in,
                              void* d_out, int out_size, void* d_ws, size_t ws_size,
                              hipStream_t stream){
  const float* x   = (const float*)d_in[0];
  const float* w1  = (const float*)d_in[1];
  const float* g1  = (const float*)d_in[3];
  const float* be1 = (const float*)d_in[4];
  const float* w2  = (const float*)d_in[5];
  const float* g2  = (const float*)d_in[7];
  const float* be2 = (const float*)d_in[8];
  const float* w3  = (const float*)d_in[9];
  const float* g3  = (const float*)d_in[11];
  const float* be3 = (const float*)d_in[12];
  const float* w4  = (const float*)d_in[13];
  const float* g4  = (const float*)d_in[15];
  const float* be4 = (const float*)d_in[16];
  const float* T   = (const float*)d_in[17];
  const float* fcw = (const float*)d_in[18];
  const float* fcb = (const float*)d_in[19];
  float* out = (float*)d_out;
  float* ws  = (float*)d_ws;

  // workspace (float units)
  unsigned short* f1raw = (unsigned short*)ws;               // 8,388,608 fl
  // Tp aliases dead f1raw after conv2: 13,107,200 shorts = 6,553,600 fl <= 8,388,608 ✓
  unsigned short* Tp    = (unsigned short*)ws;
  unsigned short* f2    = (unsigned short*)(ws + 8388608);   // 4,194,304 fl
  unsigned short* f3    = (unsigned short*)(ws + 12582912);  // 2,097,152 fl
  unsigned short* featb = (unsigned short*)(ws + 14680064);  //   524,288 fl
  unsigned short* wb1   = (unsigned short*)(ws + 15204352);  //     4,096 fl
  unsigned short* wb2   = (unsigned short*)(ws + 15208448);  //   102,400 fl
  unsigned short* wb3   = (unsigned short*)(ws + 15310848);  //   409,600 fl
  unsigned short* wb4   = (unsigned short*)(ws + 15720448);  //   294,912 fl
  float* S1    = ws + 16015360;                              //    16,384
  float* Q1    = ws + 16031744;                              //    16,384
  float* S2    = ws + 16048128;                              //    32,768
  float* Q2    = ws + 16080896;                              //    32,768  (end 16,113,664)
  float* Mp    = ws + 16113664;                              // 6,553,600
  // Wp aliases Mp (dead after reduceM): 4,259,840 shorts = 2,129,920 fl <= 6,553,600 ✓
  unsigned short* Wp  = (unsigned short*)(ws + 16113664);
  __half* Mh   = (__half*)(ws + 22667264);                   //   458,752 fl (256x3584 halfs, rows padded to 56)
  unsigned short* obb = (unsigned short*)(ws + 23142400);    //     8,192 fl
  float* yp    = ws + 23150592;                              // 3,328,000 (end 26,478,592 fl)
  float* obp   = ws + 26478592;                              //   131,072 (8 x 16384, end 26,609,664 fl)
  float* feat  = out;
  float* y     = out + 1048576;

  prep_k<<<dim3(6720), 256, 0, stream>>>(w1, w2, w3, w4, wb1, wb2, wb3, wb4, S1);

  conv1_k<<<dim3(512),     256, 0, stream>>>(x, wb1, S1, Q1, f1raw);
  conv2_k<<<dim3(512),     512, 0, stream>>>(f1raw, wb2, S1, Q1, g1, be1, S2, Q2, f2);
  packT_k<<<dim3(3200),    256, 0, stream>>>(T, Tp);
  conv3_k<<<dim3(256, 2),  512, 0, stream>>>(f2, wb3, S2, Q2, g2, be2, g3, be3, f3);
  conv4_k<<<dim3(128, 4),  256, 0, stream>>>(f3, wb4, g4, be4, feat, featb);

  gemmM_k  <<<dim3(25, 2, 8),  256, 0, stream>>>(featb, Tp, Mp);
  reduceM_k<<<dim3(3584),      256, 0, stream>>>(Mp, Mh);
  packW_k  <<<dim3(2080),      256, 0, stream>>>(fcw, Wp);
  pairv2_k <<<dim3(64, 8),     256, 0, stream>>>(Mh, obp);
  finalizeOB_k<<<dim3(64),     256, 0, stream>>>(obp, obb);
  gemmFC_k <<<dim3(8, 2, 13),  256, 0, stream>>>(featb, obb, Wp, yp);
  reduceY_k<<<dim3(1000),      256, 0, stream>>>(yp, fcb, y);
}